// Round 1
// baseline (3580.405 us; speedup 1.0000x reference)
//
#include <hip/hip_runtime.h>
#include <math.h>

#define B_SZ 2
#define N_SEQ 2048
#define DM 1024
#define H_HEADS 16
#define DH 64
#define KC 32
#define TOPK 100

// ---------- helpers ----------
__device__ __forceinline__ unsigned order_key(float f) {
  unsigned u = __float_as_uint(f);
  return (u & 0x80000000u) ? ~u : (u | 0x80000000u);  // monotone float->uint
}

// ---------- constants: Riemann-zero weights ----------
__global__ void const_kernel(float* __restrict__ wre, float* __restrict__ wim) {
  __shared__ double g0s;
  const int k = threadIdx.x;  // launched with 32 threads
  const double PI = 3.14159265358979323846;
  const double E_ = 2.71828182845904523536;
  double n = (double)(k + 1);
  double t = 10.0 + 6.0 * n;
  for (int it = 0; it < 60; ++it) {
    double f  = t / (2.0 * PI) * log(t / (2.0 * PI * E_)) - (n - 0.875);
    double fp = log(t / (2.0 * PI)) / (2.0 * PI);
    t = t - f / fp;
  }
  if (k == 0) g0s = t;
  __syncthreads();
  double g = t / g0s;
  double denom = 0.25 + g * g;
  wre[k] = (float)(0.5 / denom);
  wim[k] = (float)(-g / denom);
}

// ---------- fp32 GEMM: C[4096][1024] = A[4096][1024] @ W[1024][1024] ----------
__device__ __forceinline__ void gemm64_body(const float* __restrict__ A,
                                            const float* __restrict__ Bm,
                                            float* __restrict__ C) {
  __shared__ float As[16][64];
  __shared__ float Bs[16][64];
  const int tid = threadIdx.x;
  const int tx = tid & 15, ty = tid >> 4;
  const int bm = blockIdx.x * 64;
  const int bn = blockIdx.y * 64;
  const int mA = tid >> 2, kA = (tid & 3) * 4;
  float acc[4][4] = {};
  for (int k0 = 0; k0 < DM; k0 += 16) {
    float4 av = *(const float4*)(A + (size_t)(bm + mA) * DM + k0 + kA);
    As[kA + 0][mA] = av.x;
    As[kA + 1][mA] = av.y;
    As[kA + 2][mA] = av.z;
    As[kA + 3][mA] = av.w;
#pragma unroll
    for (int r = 0; r < 4; ++r) {
      int idx = r * 256 + tid;
      int kb = idx >> 6, nb = idx & 63;
      Bs[kb][nb] = Bm[(size_t)(k0 + kb) * DM + bn + nb];
    }
    __syncthreads();
#pragma unroll
    for (int kk = 0; kk < 16; ++kk) {
      float4 a = *(const float4*)&As[kk][ty * 4];
      float4 b = *(const float4*)&Bs[kk][tx * 4];
      acc[0][0] += a.x * b.x; acc[0][1] += a.x * b.y; acc[0][2] += a.x * b.z; acc[0][3] += a.x * b.w;
      acc[1][0] += a.y * b.x; acc[1][1] += a.y * b.y; acc[1][2] += a.y * b.z; acc[1][3] += a.y * b.w;
      acc[2][0] += a.z * b.x; acc[2][1] += a.z * b.y; acc[2][2] += a.z * b.z; acc[2][3] += a.z * b.w;
      acc[3][0] += a.w * b.x; acc[3][1] += a.w * b.y; acc[3][2] += a.w * b.z; acc[3][3] += a.w * b.w;
    }
    __syncthreads();
  }
#pragma unroll
  for (int ii = 0; ii < 4; ++ii) {
    float4 o = make_float4(acc[ii][0], acc[ii][1], acc[ii][2], acc[ii][3]);
    *(float4*)(C + (size_t)(bm + ty * 4 + ii) * DM + bn + tx * 4) = o;
  }
}

__global__ __launch_bounds__(256) void gemm_qkv(const float* __restrict__ x,
                                                const float* __restrict__ Wq,
                                                const float* __restrict__ Wk,
                                                const float* __restrict__ Wv,
                                                float* __restrict__ q,
                                                float* __restrict__ k,
                                                float* __restrict__ v) {
  const float* W;
  float* C;
  if (blockIdx.z == 0)      { W = Wq; C = q; }
  else if (blockIdx.z == 1) { W = Wk; C = k; }
  else                      { W = Wv; C = v; }
  gemm64_body(x, W, C);
}

__global__ __launch_bounds__(256) void gemm_single(const float* __restrict__ A,
                                                   const float* __restrict__ W,
                                                   float* __restrict__ C) {
  gemm64_body(A, W, C);
}

// ---------- RoPE + w-weighting + layout transform ----------
// q,k,v : (B, N, D) row-major.  Outputs qh, kt, vt : (B, H, N, 64).
// qh/kt layout: [re(0..31), im(32..63)]  so score = dot64(qh_row, kt_row).
__global__ __launch_bounds__(256) void transform_kernel(
    const float* __restrict__ q, const float* __restrict__ k,
    const float* __restrict__ v, const float* __restrict__ wre,
    const float* __restrict__ wim, float* __restrict__ qh,
    float* __restrict__ kt, float* __restrict__ vt) {
  int idx = blockIdx.x * blockDim.x + threadIdx.x;  // 2^21 threads total
  int kk = idx & 31;
  int h  = (idx >> 5) & 15;
  int n  = (idx >> 9) & 2047;
  int b  = idx >> 20;

  size_t base_in = ((size_t)(b * N_SEQ + n)) * DM + h * DH;
  float q_re = q[base_in + 2 * kk], q_im = q[base_in + 2 * kk + 1];
  float k_re = k[base_in + 2 * kk], k_im = k[base_in + 2 * kk + 1];

  double inv_freq = pow(10000.0, -(double)kk / 32.0);
  double phase = (double)n * inv_freq;
  float cp = (float)cos(phase), sp = (float)sin(phase);

  float qt_re = cp * q_re + sp * q_im;
  float qt_im = cp * q_im - sp * q_re;
  float ktr   = cp * k_re + sp * k_im;
  float kti   = cp * k_im - sp * k_re;

  float wr = wre[kk], wi = wim[kk];
  float qh_re = wr * qt_re - wi * qt_im;
  float qh_im = wr * qt_im + wi * qt_re;

  size_t base_out = ((size_t)((b * H_HEADS + h) * N_SEQ + n)) * DH;
  qh[base_out + kk]      = qh_re;
  qh[base_out + 32 + kk] = qh_im;
  kt[base_out + kk]      = ktr;
  kt[base_out + 32 + kk] = kti;
  vt[base_out + 2 * kk]     = v[base_in + 2 * kk];
  vt[base_out + 2 * kk + 1] = v[base_in + 2 * kk + 1];
}

// ---------- attention with exact top-100 per row ----------
// one workgroup (256 threads) per row (b,h,i); o : (B, N, D)
__global__ __launch_bounds__(256) void attn_kernel(const float* __restrict__ qh,
                                                   const float* __restrict__ kt,
                                                   const float* __restrict__ vt,
                                                   float* __restrict__ o) {
  __shared__ float s[N_SEQ];
  __shared__ float red[256];
  __shared__ unsigned hist[256];
  __shared__ unsigned sh_prefix;
  __shared__ int sh_k;
  __shared__ float redv[4][64];

  const int row = blockIdx.x;
  const int i = row & (N_SEQ - 1);
  const int bh = row >> 11;  // b*H + h
  const int tid = threadIdx.x;

  // load this row's qh into registers (broadcast loads, L2-resident)
  const float* qrow = qh + (size_t)(bh * N_SEQ + i) * DH;
  float qr[64];
#pragma unroll
  for (int d = 0; d < 16; ++d) {
    float4 t4 = ((const float4*)qrow)[d];
    qr[4 * d + 0] = t4.x; qr[4 * d + 1] = t4.y;
    qr[4 * d + 2] = t4.z; qr[4 * d + 3] = t4.w;
  }

  // ---- score pass ----
  const float inv1pi = 1.0f / (1.0f + (float)i);
  float lmax = -INFINITY;
  for (int j = tid; j <= i; j += 256) {
    const float4* kr = (const float4*)(kt + (size_t)(bh * N_SEQ + j) * DH);
    float dot = 0.f;
#pragma unroll
    for (int d4 = 0; d4 < 16; ++d4) {
      float4 kv = kr[d4];
      dot += qr[4 * d4 + 0] * kv.x + qr[4 * d4 + 1] * kv.y +
             qr[4 * d4 + 2] * kv.z + qr[4 * d4 + 3] * kv.w;
    }
    float sc = dot * 0.125f * sqrtf((1.0f + (float)j) * inv1pi);
    s[j] = sc;
    lmax = fmaxf(lmax, sc);
  }

  // ---- max reduce ----
  red[tid] = lmax;
  __syncthreads();
  for (int off = 128; off > 0; off >>= 1) {
    if (tid < off) red[tid] = fmaxf(red[tid], red[tid + off]);
    __syncthreads();
  }
  const float m = red[0];
  __syncthreads();

  // ---- exact 100th-largest via 4-pass radix select on orderable bits ----
  const int L = i + 1;
  unsigned Tu = 0;
  if (L > TOPK) {
    unsigned prefix = 0;
    int krem = TOPK;
    for (int pass = 3; pass >= 0; --pass) {
      const int shift = pass * 8;
      hist[tid] = 0;
      __syncthreads();
      for (int j = tid; j <= i; j += 256) {
        unsigned u = order_key(s[j]);
        bool match = (pass == 3) || (((u ^ prefix) >> (shift + 8)) == 0);
        if (match) atomicAdd(&hist[(u >> shift) & 255], 1u);
      }
      __syncthreads();
      if (tid == 0) {
        int cum = 0, bsel = 0;
        for (int b = 255; b >= 0; --b) {
          int hcur = (int)hist[b];
          if (cum + hcur >= krem) { bsel = b; break; }
          cum += hcur;
        }
        sh_prefix = prefix | ((unsigned)bsel << shift);
        sh_k = krem - cum;
      }
      __syncthreads();
      prefix = sh_prefix;
      krem = sh_k;
      __syncthreads();
    }
    Tu = prefix;  // exact key of the 100th-largest score
  }

  // ---- masked exp + sum ----
  float lsum = 0.f;
  for (int j = tid; j <= i; j += 256) {
    float sc = s[j];
    bool keep = (L <= TOPK) || (order_key(sc) >= Tu);
    float p = keep ? expf(sc - m) : 0.f;
    s[j] = p;
    lsum += p;
  }
  red[tid] = lsum;
  __syncthreads();
  for (int off = 128; off > 0; off >>= 1) {
    if (tid < off) red[tid] += red[tid + off];
    __syncthreads();
  }
  const float sum_p = red[0];
  __syncthreads();

  // ---- sparse p @ V (skip branch is wave-uniform: wave w owns j = w mod 4) ----
  const int lane_d = tid & 63;
  const int grp = tid >> 6;
  float acc = 0.f;
  for (int j = grp; j <= i; j += 4) {
    float p = s[j];  // LDS broadcast within the wave
    if (p > 0.f) acc += p * vt[(size_t)(bh * N_SEQ + j) * DH + lane_d];
  }
  redv[grp][lane_d] = acc;
  __syncthreads();
  if (grp == 0) {
    float tot = redv[0][lane_d] + redv[1][lane_d] + redv[2][lane_d] + redv[3][lane_d];
    int b = bh >> 4, h = bh & 15;
    o[((size_t)(b * N_SEQ + i)) * DM + h * DH + lane_d] = tot / sum_p;
  }
}

// ---------- launch ----------
extern "C" void kernel_launch(void* const* d_in, const int* in_sizes, int n_in,
                              void* d_out, int out_size, void* d_ws, size_t ws_size,
                              hipStream_t stream) {
  const float* x  = (const float*)d_in[0];
  const float* Wq = (const float*)d_in[1];
  const float* Wk = (const float*)d_in[2];
  const float* Wv = (const float*)d_in[3];
  const float* Wo = (const float*)d_in[4];
  float* out = (float*)d_out;
  float* ws = (float*)d_ws;

  const size_t MAT = (size_t)B_SZ * N_SEQ * DM;  // 4,194,304 elements
  float* q   = ws + 0 * MAT;
  float* k   = ws + 1 * MAT;
  float* v   = ws + 2 * MAT;
  float* qh  = ws + 3 * MAT;
  float* kt  = ws + 4 * MAT;
  float* vt  = ws + 5 * MAT;
  float* o   = q;              // q is dead after transform; reuse for attn output
  float* wre = ws + 6 * MAT;
  float* wim = wre + KC;

  const_kernel<<<1, 32, 0, stream>>>(wre, wim);
  gemm_qkv<<<dim3(64, 16, 3), 256, 0, stream>>>(x, Wq, Wk, Wv, q, k, v);
  transform_kernel<<<(B_SZ * N_SEQ * H_HEADS * KC) / 256, 256, 0, stream>>>(
      q, k, v, wre, wim, qh, kt, vt);
  attn_kernel<<<B_SZ * H_HEADS * N_SEQ, 256, 0, stream>>>(qh, kt, vt, o);
  gemm_single<<<dim3(64, 16, 1), 256, 0, stream>>>(o, Wo, out);
}

// Round 2
// 1601.493 us; speedup vs baseline: 2.2357x; 2.2357x over previous
//
#include <hip/hip_runtime.h>
#include <math.h>

#define B_SZ 2
#define N_SEQ 2048
#define DM 1024
#define H_HEADS 16
#define DH 64
#define KC 32
#define TOPK 100
#define TQ 8
#define KT 64
#define CAP 256

// ---------- helpers ----------
__device__ __forceinline__ unsigned short f2bf(float f) {
  unsigned u = __float_as_uint(f);
  unsigned r = (u + 0x7fffu + ((u >> 16) & 1u)) >> 16;  // RNE
  return (unsigned short)r;
}
__device__ __forceinline__ float bf2f(unsigned short us) {
  return __uint_as_float(((unsigned)us) << 16);
}
__device__ __forceinline__ unsigned okey16(unsigned short us) {
  return (us & 0x8000u) ? (unsigned)(unsigned short)~us
                        : (unsigned)(us | 0x8000u);
}

// ---------- constants: Riemann-zero weights ----------
__global__ void const_kernel(float* __restrict__ wre, float* __restrict__ wim) {
  __shared__ double g0s;
  const int k = threadIdx.x;  // launched with 32 threads
  const double PI = 3.14159265358979323846;
  const double E_ = 2.71828182845904523536;
  double n = (double)(k + 1);
  double t = 10.0 + 6.0 * n;
  for (int it = 0; it < 60; ++it) {
    double f  = t / (2.0 * PI) * log(t / (2.0 * PI * E_)) - (n - 0.875);
    double fp = log(t / (2.0 * PI)) / (2.0 * PI);
    t = t - f / fp;
  }
  if (k == 0) g0s = t;
  __syncthreads();
  double g = t / g0s;
  double denom = 0.25 + g * g;
  wre[k] = (float)(0.5 / denom);
  wim[k] = (float)(-g / denom);
}

// ---------- fp32 GEMM: C[4096][1024] = A[4096][1024] @ W[1024][1024] ----------
__device__ __forceinline__ void gemm64_body(const float* __restrict__ A,
                                            const float* __restrict__ Bm,
                                            float* __restrict__ C) {
  __shared__ float As[16][64];
  __shared__ float Bs[16][64];
  const int tid = threadIdx.x;
  const int tx = tid & 15, ty = tid >> 4;
  const int bm = blockIdx.x * 64;
  const int bn = blockIdx.y * 64;
  const int mA = tid >> 2, kA = (tid & 3) * 4;
  float acc[4][4] = {};
  for (int k0 = 0; k0 < DM; k0 += 16) {
    float4 av = *(const float4*)(A + (size_t)(bm + mA) * DM + k0 + kA);
    As[kA + 0][mA] = av.x;
    As[kA + 1][mA] = av.y;
    As[kA + 2][mA] = av.z;
    As[kA + 3][mA] = av.w;
#pragma unroll
    for (int r = 0; r < 4; ++r) {
      int idx = r * 256 + tid;
      int kb = idx >> 6, nb = idx & 63;
      Bs[kb][nb] = Bm[(size_t)(k0 + kb) * DM + bn + nb];
    }
    __syncthreads();
#pragma unroll
    for (int kk = 0; kk < 16; ++kk) {
      float4 a = *(const float4*)&As[kk][ty * 4];
      float4 b = *(const float4*)&Bs[kk][tx * 4];
      acc[0][0] += a.x * b.x; acc[0][1] += a.x * b.y; acc[0][2] += a.x * b.z; acc[0][3] += a.x * b.w;
      acc[1][0] += a.y * b.x; acc[1][1] += a.y * b.y; acc[1][2] += a.y * b.z; acc[1][3] += a.y * b.w;
      acc[2][0] += a.z * b.x; acc[2][1] += a.z * b.y; acc[2][2] += a.z * b.z; acc[2][3] += a.z * b.w;
      acc[3][0] += a.w * b.x; acc[3][1] += a.w * b.y; acc[3][2] += a.w * b.z; acc[3][3] += a.w * b.w;
    }
    __syncthreads();
  }
#pragma unroll
  for (int ii = 0; ii < 4; ++ii) {
    float4 o = make_float4(acc[ii][0], acc[ii][1], acc[ii][2], acc[ii][3]);
    *(float4*)(C + (size_t)(bm + ty * 4 + ii) * DM + bn + tx * 4) = o;
  }
}

__global__ __launch_bounds__(256) void gemm_qkv(const float* __restrict__ x,
                                                const float* __restrict__ Wq,
                                                const float* __restrict__ Wk,
                                                const float* __restrict__ Wv,
                                                float* __restrict__ q,
                                                float* __restrict__ k,
                                                float* __restrict__ v) {
  const float* W;
  float* C;
  if (blockIdx.z == 0)      { W = Wq; C = q; }
  else if (blockIdx.z == 1) { W = Wk; C = k; }
  else                      { W = Wv; C = v; }
  gemm64_body(x, W, C);
}

__global__ __launch_bounds__(256) void gemm_single(const float* __restrict__ A,
                                                   const float* __restrict__ W,
                                                   float* __restrict__ C) {
  gemm64_body(A, W, C);
}

// ---------- RoPE + w-weighting + layout transform ----------
__global__ __launch_bounds__(256) void transform_kernel(
    const float* __restrict__ q, const float* __restrict__ k,
    const float* __restrict__ v, const float* __restrict__ wre,
    const float* __restrict__ wim, float* __restrict__ qh,
    float* __restrict__ kt, float* __restrict__ vt) {
  int idx = blockIdx.x * blockDim.x + threadIdx.x;
  int kk = idx & 31;
  int h  = (idx >> 5) & 15;
  int n  = (idx >> 9) & 2047;
  int b  = idx >> 20;

  size_t base_in = ((size_t)(b * N_SEQ + n)) * DM + h * DH;
  float q_re = q[base_in + 2 * kk], q_im = q[base_in + 2 * kk + 1];
  float k_re = k[base_in + 2 * kk], k_im = k[base_in + 2 * kk + 1];

  double inv_freq = pow(10000.0, -(double)kk / 32.0);
  double phase = (double)n * inv_freq;
  float cp = (float)cos(phase), sp = (float)sin(phase);

  float qt_re = cp * q_re + sp * q_im;
  float qt_im = cp * q_im - sp * q_re;
  float ktr   = cp * k_re + sp * k_im;
  float kti   = cp * k_im - sp * k_re;

  float wr = wre[kk], wi = wim[kk];
  float qh_re = wr * qt_re - wi * qt_im;
  float qh_im = wr * qt_im + wi * qt_re;

  size_t base_out = ((size_t)((b * H_HEADS + h) * N_SEQ + n)) * DH;
  qh[base_out + kk]      = qh_re;
  qh[base_out + 32 + kk] = qh_im;
  kt[base_out + kk]      = ktr;
  kt[base_out + 32 + kk] = kti;
  vt[base_out + 2 * kk]     = v[base_in + 2 * kk];
  vt[base_out + 2 * kk + 1] = v[base_in + 2 * kk + 1];
}

// ---------- attention: 8 Q-rows per block, LDS-tiled K, bf16 scores ----------
__global__ __launch_bounds__(256) void attn_kernel(const float* __restrict__ qh,
                                                   const float* __restrict__ kt,
                                                   const float* __restrict__ vt,
                                                   float* __restrict__ o) {
  __shared__ unsigned short sS[TQ][N_SEQ];          // 32 KB bf16 scores
  __shared__ __align__(16) float ktile[KT][68];     // 17.4 KB padded K tile
  __shared__ unsigned hist[TQ][256];                // 8 KB
  __shared__ unsigned short lst[TQ][CAP];           // 4 KB
  __shared__ float plist[TQ][CAP];                  // 8 KB
  __shared__ float mred[TQ][64];                    // 2 KB
  __shared__ float sred[TQ][32];                    // 1 KB
  __shared__ float rowm[TQ], rowsum[TQ];
  __shared__ unsigned cnt[TQ];
  __shared__ unsigned short thr16[TQ];
  __shared__ int sh_b[TQ], sh_k[TQ];

  const int tile = blockIdx.x;   // 0..255
  const int bh   = blockIdx.y;   // 0..31
  const int i0   = tile * TQ;
  const int tid  = threadIdx.x;

  // ---- phase 1: scores ----
  const int jl = tid & 63;
  const int rg = tid >> 6;            // 0..3
  const int r0 = rg * 2, r1 = r0 + 1;
  const int i_r0 = i0 + r0, i_r1 = i0 + r1;

  const float* q0 = qh + ((size_t)(bh * N_SEQ + i_r0)) * DH;
  const float* q1 = qh + ((size_t)(bh * N_SEQ + i_r1)) * DH;
  float qa[64], qb[64];
#pragma unroll
  for (int d = 0; d < 16; ++d) {
    float4 t4 = ((const float4*)q0)[d];
    qa[4*d+0] = t4.x; qa[4*d+1] = t4.y; qa[4*d+2] = t4.z; qa[4*d+3] = t4.w;
    float4 u4 = ((const float4*)q1)[d];
    qb[4*d+0] = u4.x; qb[4*d+1] = u4.y; qb[4*d+2] = u4.z; qb[4*d+3] = u4.w;
  }
  const float rs0 = 0.125f * rsqrtf(1.0f + (float)i_r0);
  const float rs1 = 0.125f * rsqrtf(1.0f + (float)i_r1);

  const int ntile = (i0 + TQ + KT - 1) / KT;
  float mx0 = -INFINITY, mx1 = -INFINITY;
  for (int t = 0; t < ntile; ++t) {
    const int j0 = t * KT;
    __syncthreads();   // previous tile's consumers done
    // stage 64x64 K rows, coalesced
#pragma unroll
    for (int u = 0; u < 4; ++u) {
      int idx = u * 256 + tid;          // 0..1023 float4 chunks
      int row = idx >> 4, c4 = idx & 15;
      float4 kv = *(const float4*)(kt + ((size_t)(bh * N_SEQ + j0 + row)) * DH + c4 * 4);
      *(float4*)&ktile[row][c4 * 4] = kv;
    }
    __syncthreads();
    const int j = j0 + jl;
    float dot0 = 0.f, dot1 = 0.f;
#pragma unroll
    for (int d4 = 0; d4 < 16; ++d4) {
      float4 kv = *(const float4*)&ktile[jl][d4 * 4];
      dot0 += qa[4*d4+0]*kv.x + qa[4*d4+1]*kv.y + qa[4*d4+2]*kv.z + qa[4*d4+3]*kv.w;
      dot1 += qb[4*d4+0]*kv.x + qb[4*d4+1]*kv.y + qb[4*d4+2]*kv.z + qb[4*d4+3]*kv.w;
    }
    const float sj = sqrtf(1.0f + (float)j);
    const float sc0 = dot0 * rs0 * sj;
    const float sc1 = dot1 * rs1 * sj;
    sS[r0][j] = f2bf(sc0);
    sS[r1][j] = f2bf(sc1);
    if (j <= i_r0) mx0 = fmaxf(mx0, sc0);
    if (j <= i_r1) mx1 = fmaxf(mx1, sc1);
  }
  mred[r0][jl] = mx0;
  mred[r1][jl] = mx1;
  __syncthreads();
  if (tid < TQ) {
    float m = -INFINITY;
    for (int l = 0; l < 64; ++l) m = fmaxf(m, mred[tid][l]);
    rowm[tid] = m;
  }
  __syncthreads();

  // ---- phase 2: exact 100th-largest bf16 key (2-pass radix-8) ----
  const int r  = tid >> 5, ts = tid & 31;
  const int i_r = i0 + r, L = i_r + 1;
  for (int u = tid; u < TQ * 256; u += 256) ((unsigned*)hist)[u] = 0;
  __syncthreads();
  if (L > TOPK) {
    for (int j = ts; j <= i_r; j += 32)
      atomicAdd(&hist[r][okey16(sS[r][j]) >> 8], 1u);
  }
  __syncthreads();
  if (ts == 0 && L > TOPK) {
    int cum = 0, b = 255;
    for (; b > 0; --b) { int h = (int)hist[r][b]; if (cum + h >= TOPK) break; cum += h; }
    sh_b[r] = b; sh_k[r] = TOPK - cum;
  }
  __syncthreads();
  const int bhi = (L > TOPK) ? sh_b[r] : 0;
  const int krem = (L > TOPK) ? sh_k[r] : 0;
  __syncthreads();
  for (int u = tid; u < TQ * 256; u += 256) ((unsigned*)hist)[u] = 0;
  __syncthreads();
  if (L > TOPK) {
    for (int j = ts; j <= i_r; j += 32) {
      unsigned key = okey16(sS[r][j]);
      if ((int)(key >> 8) == bhi) atomicAdd(&hist[r][key & 255], 1u);
    }
  }
  __syncthreads();
  if (ts == 0) {
    if (L > TOPK) {
      int cum = 0, b = 255;
      for (; b > 0; --b) { int h = (int)hist[r][b]; if (cum + h >= krem) break; cum += h; }
      thr16[r] = (unsigned short)((bhi << 8) | b);
    } else {
      thr16[r] = 0;  // keep everything
    }
    cnt[r] = 0;
  }
  __syncthreads();

  // ---- phase 3: masked exp + sum + survivor compaction ----
  {
    const unsigned T16 = okey16(thr16[r]) * 0u + (unsigned)thr16[r]; // thr16 already a key? no:
  }
  // NOTE: thr16 stores the KEY (bhi<<8|b) directly; compare okey16(score) >= key.
  float lsum = 0.f;
  const unsigned Tkey = (unsigned)thr16[r];
  const float m = rowm[r];
  for (int j = ts; j <= i_r; j += 32) {
    unsigned short us = sS[r][j];
    if (okey16(us) >= Tkey) {
      float p = expf(bf2f(us) - m);
      unsigned pos = atomicAdd(&cnt[r], 1u);
      if (pos < CAP) { lst[r][pos] = (unsigned short)j; plist[r][pos] = p; }
      lsum += p;
    }
  }
  sred[r][ts] = lsum;
  __syncthreads();
  if (ts == 0) {
    float s = 0.f;
    for (int l = 0; l < 32; ++l) s += sred[r][l];
    rowsum[r] = s;
  }
  __syncthreads();

  // ---- phase 4: sparse p @ V, one wave per row ----
  const int w = tid >> 6;
  const int lane = tid & 63;
  for (int rr = w; rr < TQ; rr += 4) {
    const int n = (int)min(cnt[rr], (unsigned)CAP);
    float acc = 0.f;
    for (int s = 0; s < n; ++s) {
      const int jj = lst[rr][s];
      const float p = plist[rr][s];
      acc += p * vt[((size_t)(bh * N_SEQ + jj)) * DH + lane];
    }
    const int b = bh >> 4, h = bh & 15;
    const int i = i0 + rr;
    o[((size_t)(b * N_SEQ + i)) * DM + h * DH + lane] = acc / rowsum[rr];
  }
}

// ---------- launch ----------
extern "C" void kernel_launch(void* const* d_in, const int* in_sizes, int n_in,
                              void* d_out, int out_size, void* d_ws, size_t ws_size,
                              hipStream_t stream) {
  const float* x  = (const float*)d_in[0];
  const float* Wq = (const float*)d_in[1];
  const float* Wk = (const float*)d_in[2];
  const float* Wv = (const float*)d_in[3];
  const float* Wo = (const float*)d_in[4];
  float* out = (float*)d_out;
  float* ws = (float*)d_ws;

  const size_t MAT = (size_t)B_SZ * N_SEQ * DM;  // 4,194,304 elements
  float* q   = ws + 0 * MAT;
  float* k   = ws + 1 * MAT;
  float* v   = ws + 2 * MAT;
  float* qh  = ws + 3 * MAT;
  float* kt  = ws + 4 * MAT;
  float* vt  = ws + 5 * MAT;
  float* o   = q;              // q is dead after transform; reuse for attn output
  float* wre = ws + 6 * MAT;
  float* wim = wre + KC;

  const_kernel<<<1, 32, 0, stream>>>(wre, wim);
  gemm_qkv<<<dim3(64, 16, 3), 256, 0, stream>>>(x, Wq, Wk, Wv, q, k, v);
  transform_kernel<<<(B_SZ * N_SEQ * H_HEADS * KC) / 256, 256, 0, stream>>>(
      q, k, v, wre, wim, qh, kt, vt);
  attn_kernel<<<dim3(N_SEQ / TQ, B_SZ * H_HEADS), 256, 0, stream>>>(qh, kt, vt, o);
  gemm_single<<<dim3(64, 16, 1), 256, 0, stream>>>(o, Wo, out);
}

// Round 3
// 1348.809 us; speedup vs baseline: 2.6545x; 1.1873x over previous
//
#include <hip/hip_runtime.h>
#include <math.h>

#define B_SZ 2
#define N_SEQ 2048
#define DM 1024
#define H_HEADS 16
#define DH 64
#define KC 32
#define TOPK 100
#define TQ 8
#define KT 64
#define CAP 256

typedef _Float16 half2_t __attribute__((ext_vector_type(2)));
typedef _Float16 half4_t __attribute__((ext_vector_type(4)));
typedef _Float16 half8_t __attribute__((ext_vector_type(8)));

#if __has_builtin(__builtin_amdgcn_fdot2)
#define FDOT2(a, b, c) __builtin_amdgcn_fdot2((a), (b), (c), false)
#else
#define FDOT2(a, b, c) \
  ((c) + (float)(a)[0] * (float)(b)[0] + (float)(a)[1] * (float)(b)[1])
#endif

// ---------- helpers ----------
__device__ __forceinline__ unsigned short h2us(_Float16 h) {
  unsigned short u; __builtin_memcpy(&u, &h, 2); return u;
}
__device__ __forceinline__ _Float16 us2h(unsigned short u) {
  _Float16 h; __builtin_memcpy(&h, &u, 2); return h;
}
__device__ __forceinline__ unsigned okey16(unsigned short us) {
  return (us & 0x8000u) ? (unsigned)(unsigned short)~us
                        : (unsigned)(us | 0x8000u);
}

// ---------- constants: Riemann-zero weights ----------
__global__ void const_kernel(float* __restrict__ wre, float* __restrict__ wim) {
  __shared__ double g0s;
  const int k = threadIdx.x;  // launched with 32 threads
  const double PI = 3.14159265358979323846;
  const double E_ = 2.71828182845904523536;
  double n = (double)(k + 1);
  double t = 10.0 + 6.0 * n;
  for (int it = 0; it < 60; ++it) {
    double f  = t / (2.0 * PI) * log(t / (2.0 * PI * E_)) - (n - 0.875);
    double fp = log(t / (2.0 * PI)) / (2.0 * PI);
    t = t - f / fp;
  }
  if (k == 0) g0s = t;
  __syncthreads();
  double g = t / g0s;
  double denom = 0.25 + g * g;
  wre[k] = (float)(0.5 / denom);
  wim[k] = (float)(-g / denom);
}

// ---------- RoPE tables: cos/sin of n * 10000^(-k/32) ----------
__global__ __launch_bounds__(256) void rope_kernel(float* __restrict__ cosT,
                                                   float* __restrict__ sinT) {
  int idx = blockIdx.x * 256 + threadIdx.x;  // 65536 = 2048*32
  int kk = idx & 31, n = idx >> 5;
  double inv_freq = pow(10000.0, -(double)kk / 32.0);
  double ph = (double)n * inv_freq;
  cosT[idx] = (float)cos(ph);
  sinT[idx] = (float)sin(ph);
}

// ---------- fp32 GEMM: C[4096][1024] = A[4096][1024] @ W[1024][1024] ----------
__device__ __forceinline__ void gemm64_body(const float* __restrict__ A,
                                            const float* __restrict__ Bm,
                                            float* __restrict__ C) {
  __shared__ float As[16][64];
  __shared__ float Bs[16][64];
  const int tid = threadIdx.x;
  const int tx = tid & 15, ty = tid >> 4;
  const int bm = blockIdx.x * 64;
  const int bn = blockIdx.y * 64;
  const int mA = tid >> 2, kA = (tid & 3) * 4;
  float acc[4][4] = {};
  for (int k0 = 0; k0 < DM; k0 += 16) {
    float4 av = *(const float4*)(A + (size_t)(bm + mA) * DM + k0 + kA);
    As[kA + 0][mA] = av.x;
    As[kA + 1][mA] = av.y;
    As[kA + 2][mA] = av.z;
    As[kA + 3][mA] = av.w;
#pragma unroll
    for (int r = 0; r < 4; ++r) {
      int idx = r * 256 + tid;
      int kb = idx >> 6, nb = idx & 63;
      Bs[kb][nb] = Bm[(size_t)(k0 + kb) * DM + bn + nb];
    }
    __syncthreads();
#pragma unroll
    for (int kk = 0; kk < 16; ++kk) {
      float4 a = *(const float4*)&As[kk][ty * 4];
      float4 b = *(const float4*)&Bs[kk][tx * 4];
      acc[0][0] += a.x * b.x; acc[0][1] += a.x * b.y; acc[0][2] += a.x * b.z; acc[0][3] += a.x * b.w;
      acc[1][0] += a.y * b.x; acc[1][1] += a.y * b.y; acc[1][2] += a.y * b.z; acc[1][3] += a.y * b.w;
      acc[2][0] += a.z * b.x; acc[2][1] += a.z * b.y; acc[2][2] += a.z * b.z; acc[2][3] += a.z * b.w;
      acc[3][0] += a.w * b.x; acc[3][1] += a.w * b.y; acc[3][2] += a.w * b.z; acc[3][3] += a.w * b.w;
    }
    __syncthreads();
  }
#pragma unroll
  for (int ii = 0; ii < 4; ++ii) {
    float4 o = make_float4(acc[ii][0], acc[ii][1], acc[ii][2], acc[ii][3]);
    *(float4*)(C + (size_t)(bm + ty * 4 + ii) * DM + bn + tx * 4) = o;
  }
}

__global__ __launch_bounds__(256) void gemm_qkv(const float* __restrict__ x,
                                                const float* __restrict__ Wq,
                                                const float* __restrict__ Wk,
                                                const float* __restrict__ Wv,
                                                float* __restrict__ q,
                                                float* __restrict__ k,
                                                float* __restrict__ v) {
  const float* W;
  float* C;
  if (blockIdx.z == 0)      { W = Wq; C = q; }
  else if (blockIdx.z == 1) { W = Wk; C = k; }
  else                      { W = Wv; C = v; }
  gemm64_body(x, W, C);
}

__global__ __launch_bounds__(256) void gemm_single(const float* __restrict__ A,
                                                   const float* __restrict__ W,
                                                   float* __restrict__ C) {
  gemm64_body(A, W, C);
}

// ---------- RoPE + w-weighting + layout transform ----------
__global__ __launch_bounds__(256) void transform_kernel(
    const float* __restrict__ q, const float* __restrict__ k,
    const float* __restrict__ v, const float* __restrict__ wre,
    const float* __restrict__ wim, const float* __restrict__ cosT,
    const float* __restrict__ sinT, float* __restrict__ qh,
    float* __restrict__ kt, float* __restrict__ vt) {
  int idx = blockIdx.x * blockDim.x + threadIdx.x;
  int kk = idx & 31;
  int h  = (idx >> 5) & 15;
  int n  = (idx >> 9) & 2047;
  int b  = idx >> 20;

  size_t base_in = ((size_t)(b * N_SEQ + n)) * DM + h * DH;
  float q_re = q[base_in + 2 * kk], q_im = q[base_in + 2 * kk + 1];
  float k_re = k[base_in + 2 * kk], k_im = k[base_in + 2 * kk + 1];

  float cp = cosT[n * 32 + kk], sp = sinT[n * 32 + kk];

  float qt_re = cp * q_re + sp * q_im;
  float qt_im = cp * q_im - sp * q_re;
  float ktr   = cp * k_re + sp * k_im;
  float kti   = cp * k_im - sp * k_re;

  float wr = wre[kk], wi = wim[kk];
  float qh_re = wr * qt_re - wi * qt_im;
  float qh_im = wr * qt_im + wi * qt_re;

  size_t base_out = ((size_t)((b * H_HEADS + h) * N_SEQ + n)) * DH;
  qh[base_out + kk]      = qh_re;
  qh[base_out + 32 + kk] = qh_im;
  kt[base_out + kk]      = ktr;
  kt[base_out + 32 + kk] = kti;
  vt[base_out + 2 * kk]     = v[base_in + 2 * kk];
  vt[base_out + 2 * kk + 1] = v[base_in + 2 * kk + 1];
}

// ---------- attention: 8 Q-rows/block, fp16 dot2 scores, fused radix pass 1 ----
__global__ __launch_bounds__(256) void attn_kernel(const float* __restrict__ qh,
                                                   const float* __restrict__ kt,
                                                   const float* __restrict__ vt,
                                                   float* __restrict__ o) {
  __shared__ unsigned short sS[TQ][N_SEQ];         // 32 KB fp16 scores
  __shared__ __align__(16) unsigned char uni[KT * 72 * 2];  // 9.2 KB union
  __shared__ unsigned hist[TQ][128];               // 4 KB packed 16-bit counts
  __shared__ float rowm[TQ], rowsum[TQ];
  __shared__ unsigned cnt[TQ], thrk[TQ];
  __shared__ int sh_b[TQ], sh_k[TQ];

  _Float16 (*ktile)[72] = (_Float16(*)[72])uni;            // phase 1
  unsigned short (*lst)[CAP] = (unsigned short(*)[CAP])uni; // phase 3+

  const int tile = gridDim.x - 1 - blockIdx.x;  // heavy blocks first
  const int bh   = blockIdx.y;                  // 0..31
  const int i0   = tile * TQ;
  const int tid  = threadIdx.x;

  // zero pass-1 histogram (visible after first barrier in score loop)
#pragma unroll
  for (int u = 0; u < 4; ++u) ((unsigned*)hist)[u * 256 + tid] = 0;

  // ---- phase 1: scores (fp16 dot2) + fused hi-byte histogram ----
  const int jl = tid & 63;
  const int rg = tid >> 6;             // wave id 0..3
  const int r0 = rg * 2, r1 = r0 + 1;
  const int i_r0 = i0 + r0, i_r1 = i0 + r1;

  const float* q0 = qh + ((size_t)(bh * N_SEQ + i_r0)) * DH;
  const float* q1 = qh + ((size_t)(bh * N_SEQ + i_r1)) * DH;
  half2_t qa[32], qb[32];
#pragma unroll
  for (int d = 0; d < 16; ++d) {
    float4 t4 = ((const float4*)q0)[d];
    half2_t a0; a0[0] = (_Float16)t4.x; a0[1] = (_Float16)t4.y;
    half2_t a1; a1[0] = (_Float16)t4.z; a1[1] = (_Float16)t4.w;
    qa[2 * d] = a0; qa[2 * d + 1] = a1;
    float4 u4 = ((const float4*)q1)[d];
    half2_t b0; b0[0] = (_Float16)u4.x; b0[1] = (_Float16)u4.y;
    half2_t b1; b1[0] = (_Float16)u4.z; b1[1] = (_Float16)u4.w;
    qb[2 * d] = b0; qb[2 * d + 1] = b1;
  }
  const float rs0 = 0.125f * rsqrtf(1.0f + (float)i_r0);
  const float rs1 = 0.125f * rsqrtf(1.0f + (float)i_r1);

  const int ntile = (i0 + TQ + KT - 1) / KT;
  float mx0 = -INFINITY, mx1 = -INFINITY;
  for (int t = 0; t < ntile; ++t) {
    const int j0 = t * KT;
    __syncthreads();  // prev consumers done (also covers hist zero-init)
    // stage 64 K rows as fp16, stride 72 halves (conflict-free b128 reads)
#pragma unroll
    for (int u = 0; u < 4; ++u) {
      int idx = u * 256 + tid;  // 1024 float4 chunks
      int row = idx >> 4, c4 = idx & 15;
      float4 kv = *(const float4*)(kt + ((size_t)(bh * N_SEQ + j0 + row)) * DH + c4 * 4);
      half4_t hv;
      hv[0] = (_Float16)kv.x; hv[1] = (_Float16)kv.y;
      hv[2] = (_Float16)kv.z; hv[3] = (_Float16)kv.w;
      *(half4_t*)&ktile[row][c4 * 4] = hv;
    }
    __syncthreads();
    const int j = j0 + jl;
    float dot0 = 0.f, dot1 = 0.f;
    const _Float16* krow = ktile[jl];
#pragma unroll
    for (int d8 = 0; d8 < 8; ++d8) {
      half8_t kv = *(const half8_t*)(krow + d8 * 8);
      half2_t k0; k0[0] = kv[0]; k0[1] = kv[1];
      half2_t k1; k1[0] = kv[2]; k1[1] = kv[3];
      half2_t k2; k2[0] = kv[4]; k2[1] = kv[5];
      half2_t k3; k3[0] = kv[6]; k3[1] = kv[7];
      dot0 = FDOT2(qa[4 * d8 + 0], k0, dot0);
      dot0 = FDOT2(qa[4 * d8 + 1], k1, dot0);
      dot0 = FDOT2(qa[4 * d8 + 2], k2, dot0);
      dot0 = FDOT2(qa[4 * d8 + 3], k3, dot0);
      dot1 = FDOT2(qb[4 * d8 + 0], k0, dot1);
      dot1 = FDOT2(qb[4 * d8 + 1], k1, dot1);
      dot1 = FDOT2(qb[4 * d8 + 2], k2, dot1);
      dot1 = FDOT2(qb[4 * d8 + 3], k3, dot1);
    }
    const float sj = sqrtf(1.0f + (float)j);
    const float sc0 = dot0 * rs0 * sj;
    const float sc1 = dot1 * rs1 * sj;
    unsigned short us0 = h2us((_Float16)sc0);
    unsigned short us1 = h2us((_Float16)sc1);
    sS[r0][j] = us0;
    sS[r1][j] = us1;
    if (j <= i_r0) {
      mx0 = fmaxf(mx0, sc0);
      unsigned key = okey16(us0);
      atomicAdd(&hist[r0][(key >> 8) >> 1], 1u << (((key >> 8) & 1) * 16));
    }
    if (j <= i_r1) {
      mx1 = fmaxf(mx1, sc1);
      unsigned key = okey16(us1);
      atomicAdd(&hist[r1][(key >> 8) >> 1], 1u << (((key >> 8) & 1) * 16));
    }
  }
  // wave-level max reduce (rows r0,r1 owned wholly by this wave)
#pragma unroll
  for (int mgap = 32; mgap; mgap >>= 1) {
    mx0 = fmaxf(mx0, __shfl_xor(mx0, mgap));
    mx1 = fmaxf(mx1, __shfl_xor(mx1, mgap));
  }
  if (jl == 0) { rowm[r0] = mx0; rowm[r1] = mx1; }
  __syncthreads();

  // ---- select hi byte (8 threads, one per row) ----
  if (tid < TQ) {
    const int i_r = i0 + tid, L = i_r + 1;
    if (L > TOPK) {
      int cum = 0, b = 255;
      for (; b > 0; --b) {
        int h = (hist[tid][b >> 1] >> ((b & 1) * 16)) & 0xffff;
        if (cum + h >= TOPK) break;
        cum += h;
      }
      sh_b[tid] = b; sh_k[tid] = TOPK - cum;
    }
  }
  __syncthreads();
  // re-zero histogram for the refine pass
#pragma unroll
  for (int u = 0; u < 4; ++u) ((unsigned*)hist)[u * 256 + tid] = 0;
  __syncthreads();

  // ---- refine pass: histogram lo byte within boundary bucket ----
  {
    const int r = tid >> 5, ts = tid & 31;
    const int i_r = i0 + r, L = i_r + 1;
    if (L > TOPK) {
      const unsigned bhi = (unsigned)sh_b[r];
      for (int j = ts; j <= i_r; j += 32) {
        unsigned key = okey16(sS[r][j]);
        if ((key >> 8) == bhi)
          atomicAdd(&hist[r][(key & 255) >> 1], 1u << ((key & 1) * 16));
      }
    }
  }
  __syncthreads();
  if (tid < TQ) {
    const int i_r = i0 + tid, L = i_r + 1;
    unsigned tk = 0;
    if (L > TOPK) {
      int krem = sh_k[tid], cum = 0, b = 255;
      for (; b > 0; --b) {
        int h = (hist[tid][b >> 1] >> ((b & 1) * 16)) & 0xffff;
        if (cum + h >= krem) break;
        cum += h;
      }
      tk = ((unsigned)sh_b[tid] << 8) | (unsigned)b;
    }
    thrk[tid] = tk;
    cnt[tid] = 0;
  }
  __syncthreads();

  // ---- masked exp + sum + survivor compaction (lst aliases ktile) ----
  {
    const int r = tid >> 5, ts = tid & 31;
    const int i_r = i0 + r;
    const unsigned tk = thrk[r];
    const float m = rowm[r];
    float lsum = 0.f;
    for (int j = ts; j <= i_r; j += 32) {
      unsigned short us = sS[r][j];
      if (okey16(us) >= tk) {
        float p = expf((float)us2h(us) - m);
        lsum += p;
        unsigned pos = atomicAdd(&cnt[r], 1u);
        if (pos < CAP) lst[r][pos] = (unsigned short)j;
      }
    }
#pragma unroll
    for (int mgap = 16; mgap; mgap >>= 1) lsum += __shfl_xor(lsum, mgap);
    if (ts == 0) rowsum[r] = lsum;
  }
  __syncthreads();

  // ---- sparse p @ V, one wave per row pair ----
  const int w = tid >> 6;
  const int lane = tid & 63;
  for (int rr = w; rr < TQ; rr += 4) {
    int n = (int)cnt[rr];
    if (n > CAP) n = CAP;
    const float m = rowm[rr];
    const float inv = 1.0f / rowsum[rr];
    float acc = 0.f;
    for (int s = 0; s < n; ++s) {
      const int jj = lst[rr][s];
      const float p = expf((float)us2h(sS[rr][jj]) - m);
      acc += p * vt[((size_t)(bh * N_SEQ + jj)) * DH + lane];
    }
    const int b = bh >> 4, h = bh & 15;
    const int i = i0 + rr;
    o[((size_t)(b * N_SEQ + i)) * DM + h * DH + lane] = acc * inv;
  }
}

// ---------- launch ----------
extern "C" void kernel_launch(void* const* d_in, const int* in_sizes, int n_in,
                              void* d_out, int out_size, void* d_ws, size_t ws_size,
                              hipStream_t stream) {
  const float* x  = (const float*)d_in[0];
  const float* Wq = (const float*)d_in[1];
  const float* Wk = (const float*)d_in[2];
  const float* Wv = (const float*)d_in[3];
  const float* Wo = (const float*)d_in[4];
  float* out = (float*)d_out;
  float* ws = (float*)d_ws;

  const size_t MAT = (size_t)B_SZ * N_SEQ * DM;  // 4,194,304 elements
  float* q    = ws + 0 * MAT;
  float* k    = ws + 1 * MAT;
  float* v    = ws + 2 * MAT;
  float* qh   = ws + 3 * MAT;
  float* kt   = ws + 4 * MAT;
  float* vt   = ws + 5 * MAT;
  float* o    = q;  // q dead after transform; reuse for attn output
  float* wre  = ws + 6 * MAT;
  float* wim  = wre + KC;
  float* cosT = wim + KC;
  float* sinT = cosT + (size_t)N_SEQ * KC;

  const_kernel<<<1, 32, 0, stream>>>(wre, wim);
  rope_kernel<<<(N_SEQ * KC) / 256, 256, 0, stream>>>(cosT, sinT);
  gemm_qkv<<<dim3(64, 16, 3), 256, 0, stream>>>(x, Wq, Wk, Wv, q, k, v);
  transform_kernel<<<(B_SZ * N_SEQ * H_HEADS * KC) / 256, 256, 0, stream>>>(
      q, k, v, wre, wim, cosT, sinT, qh, kt, vt);
  attn_kernel<<<dim3(N_SEQ / TQ, B_SZ * H_HEADS), 256, 0, stream>>>(qh, kt, vt, o);
  gemm_single<<<dim3(64, 16, 1), 256, 0, stream>>>(o, Wo, out);
}

// Round 4
// 919.317 us; speedup vs baseline: 3.8946x; 1.4672x over previous
//
#include <hip/hip_runtime.h>
#include <math.h>

#define B_SZ 2
#define N_SEQ 2048
#define DM 1024
#define H_HEADS 16
#define DH 64
#define KC 32
#define TOPK 100
#define TQ 8
#define KT 64
#define CAP 256

typedef _Float16 half2_t __attribute__((ext_vector_type(2)));
typedef _Float16 half4_t __attribute__((ext_vector_type(4)));
typedef _Float16 half8_t __attribute__((ext_vector_type(8)));
typedef float floatx4 __attribute__((ext_vector_type(4)));

#if __has_builtin(__builtin_amdgcn_fdot2)
#define FDOT2(a, b, c) __builtin_amdgcn_fdot2((a), (b), (c), false)
#else
#define FDOT2(a, b, c) \
  ((c) + (float)(a)[0] * (float)(b)[0] + (float)(a)[1] * (float)(b)[1])
#endif

// ---------- helpers ----------
__device__ __forceinline__ unsigned short h2us(_Float16 h) {
  unsigned short u; __builtin_memcpy(&u, &h, 2); return u;
}
__device__ __forceinline__ _Float16 us2h(unsigned short u) {
  _Float16 h; __builtin_memcpy(&h, &u, 2); return h;
}
__device__ __forceinline__ unsigned okey16(unsigned short us) {
  return (us & 0x8000u) ? (unsigned)(unsigned short)~us
                        : (unsigned)(us | 0x8000u);
}

// async global->LDS, 16 B per lane; lds_base must be wave-uniform
__device__ __forceinline__ void stage16(const _Float16* g, _Float16* lds_base,
                                        int lane) {
#if __has_builtin(__builtin_amdgcn_global_load_lds)
  __builtin_amdgcn_global_load_lds(
      (const __attribute__((address_space(1))) void*)g,
      (__attribute__((address_space(3))) void*)lds_base, 16, 0, 0);
#else
  *(half8_t*)(lds_base + lane * 8) = *(const half8_t*)g;
#endif
}

// ---------- constants: Riemann-zero weights ----------
__global__ void const_kernel(float* __restrict__ wre, float* __restrict__ wim) {
  __shared__ double g0s;
  const int k = threadIdx.x;  // 32 threads
  const double PI = 3.14159265358979323846;
  const double E_ = 2.71828182845904523536;
  double n = (double)(k + 1);
  double t = 10.0 + 6.0 * n;
  for (int it = 0; it < 60; ++it) {
    double f  = t / (2.0 * PI) * log(t / (2.0 * PI * E_)) - (n - 0.875);
    double fp = log(t / (2.0 * PI)) / (2.0 * PI);
    t = t - f / fp;
  }
  if (k == 0) g0s = t;
  __syncthreads();
  double g = t / g0s;
  double denom = 0.25 + g * g;
  wre[k] = (float)(0.5 / denom);
  wim[k] = (float)(-g / denom);
}

// ---------- RoPE tables ----------
__global__ __launch_bounds__(256) void rope_kernel(float* __restrict__ cosT,
                                                   float* __restrict__ sinT) {
  int idx = blockIdx.x * 256 + threadIdx.x;  // 65536 = 2048*32
  int kk = idx & 31, n = idx >> 5;
  double inv_freq = pow(10000.0, -(double)kk / 32.0);
  double ph = (double)n * inv_freq;
  cosT[idx] = (float)cos(ph);
  sinT[idx] = (float)sin(ph);
}

// ---------- cast x fp32 -> fp16 ----------
__global__ __launch_bounds__(256) void cast_x(const float* __restrict__ x,
                                              _Float16* __restrict__ xh) {
  int idx = blockIdx.x * 256 + threadIdx.x;
  float4 v = ((const float4*)x)[idx];
  half4_t h;
  h[0] = (_Float16)v.x; h[1] = (_Float16)v.y;
  h[2] = (_Float16)v.z; h[3] = (_Float16)v.w;
  ((half4_t*)xh)[idx] = h;
}

// ---------- transpose-cast W (fp32 [k][n]) -> Wt (fp16 [n][k]) ----------
__global__ __launch_bounds__(256) void transpose_cast(
    const float* __restrict__ W0, const float* __restrict__ W1,
    const float* __restrict__ W2, const float* __restrict__ W3,
    _Float16* __restrict__ T0, _Float16* __restrict__ T1,
    _Float16* __restrict__ T2, _Float16* __restrict__ T3) {
  __shared__ float t[64][65];
  const float* W; _Float16* T;
  switch (blockIdx.z) {
    case 0: W = W0; T = T0; break;
    case 1: W = W1; T = T1; break;
    case 2: W = W2; T = T2; break;
    default: W = W3; T = T3; break;
  }
  const int bx = blockIdx.x;  // k block
  const int by = blockIdx.y;  // n block
  const int tid = threadIdx.x;
  const int c = tid & 15, rr = tid >> 4;
#pragma unroll
  for (int i = 0; i < 4; ++i) {
    int k = rr + i * 16;
    float4 v = *(const float4*)(W + (size_t)(bx * 64 + k) * DM + by * 64 + c * 4);
    t[k][c * 4 + 0] = v.x; t[k][c * 4 + 1] = v.y;
    t[k][c * 4 + 2] = v.z; t[k][c * 4 + 3] = v.w;
  }
  __syncthreads();
#pragma unroll
  for (int i = 0; i < 4; ++i) {
    int n = rr + i * 16;
    half4_t h;
    h[0] = (_Float16)t[c * 4 + 0][n];
    h[1] = (_Float16)t[c * 4 + 1][n];
    h[2] = (_Float16)t[c * 4 + 2][n];
    h[3] = (_Float16)t[c * 4 + 3][n];
    *(half4_t*)(T + (size_t)(by * 64 + n) * DM + bx * 64 + c * 4) = h;
  }
}

// ---------- f16 MFMA GEMM: C[M][1024] = A[M][1024] @ Bt[1024][1024]^T ----------
// 128x128 tile, BK=32, 4 waves (2x2), 16 MFMAs/wave/K-step (m97 structure)
template <typename OutT>
__device__ __forceinline__ void gemm_mfma_body(const _Float16* __restrict__ A,
                                               const _Float16* __restrict__ Bt,
                                               OutT* __restrict__ C) {
  __shared__ _Float16 As[128 * 32];
  __shared__ _Float16 Bs[128 * 32];
  const int tid = threadIdx.x;
  const int wave = tid >> 6, lane = tid & 63;
  const int wm = wave >> 1, wn = wave & 1;
  const int bm = blockIdx.x * 128, bn = blockIdx.y * 128;
  const int lrow = lane >> 2;       // 0..15 within a 16-row segment
  const int lkb = (lane & 3) * 8;   // k element offset of this lane's 16B
  const int l16 = lane & 15, lq = lane >> 4;
  floatx4 acc[4][4] = {};

  for (int k0 = 0; k0 < DM; k0 += 32) {
    __syncthreads();
#pragma unroll
    for (int s2 = 0; s2 < 2; ++s2) {
      const int seg = wave * 2 + s2;  // 16-row segment of the 128-row tile
      stage16(A + (size_t)(bm + seg * 16 + lrow) * DM + k0 + lkb,
              As + seg * 512, lane);
      stage16(Bt + (size_t)(bn + seg * 16 + lrow) * DM + k0 + lkb,
              Bs + seg * 512, lane);
    }
    __syncthreads();
    half8_t af[4], bf[4];
#pragma unroll
    for (int mi = 0; mi < 4; ++mi)
      af[mi] = *(const half8_t*)(As + (wm * 64 + mi * 16 + l16) * 32 + lq * 8);
#pragma unroll
    for (int ni = 0; ni < 4; ++ni)
      bf[ni] = *(const half8_t*)(Bs + (wn * 64 + ni * 16 + l16) * 32 + lq * 8);
#pragma unroll
    for (int mi = 0; mi < 4; ++mi)
#pragma unroll
      for (int ni = 0; ni < 4; ++ni)
        acc[mi][ni] = __builtin_amdgcn_mfma_f32_16x16x32_f16(
            af[mi], bf[ni], acc[mi][ni], 0, 0, 0);
  }
  // epilogue: C/D layout col=lane&15, row=(lane>>4)*4+reg  [m89-verified]
#pragma unroll
  for (int mi = 0; mi < 4; ++mi)
#pragma unroll
    for (int ni = 0; ni < 4; ++ni) {
      const int col = bn + wn * 64 + ni * 16 + l16;
#pragma unroll
      for (int r = 0; r < 4; ++r) {
        const int row = bm + wm * 64 + mi * 16 + lq * 4 + r;
        C[(size_t)row * DM + col] = (OutT)acc[mi][ni][r];
      }
    }
}

__global__ __launch_bounds__(256) void gemm_qkv_mfma(
    const _Float16* __restrict__ xh, const _Float16* __restrict__ Wt0,
    const _Float16* __restrict__ Wt1, const _Float16* __restrict__ Wt2,
    _Float16* __restrict__ q, _Float16* __restrict__ k,
    _Float16* __restrict__ v) {
  const _Float16* Bt; _Float16* C;
  if (blockIdx.z == 0)      { Bt = Wt0; C = q; }
  else if (blockIdx.z == 1) { Bt = Wt1; C = k; }
  else                      { Bt = Wt2; C = v; }
  gemm_mfma_body<_Float16>(xh, Bt, C);
}

__global__ __launch_bounds__(256) void gemm_out_mfma(
    const _Float16* __restrict__ A, const _Float16* __restrict__ Bt,
    float* __restrict__ C) {
  gemm_mfma_body<float>(A, Bt, C);
}

// ---------- RoPE + w-weighting + layout transform (fp16 in, mixed out) ------
// kth rows pre-scaled by 0.125*sqrt(1+n); vth fp16; qh fp32
__global__ __launch_bounds__(256) void transform_kernel(
    const _Float16* __restrict__ q, const _Float16* __restrict__ k,
    const _Float16* __restrict__ v, const float* __restrict__ wre,
    const float* __restrict__ wim, const float* __restrict__ cosT,
    const float* __restrict__ sinT, float* __restrict__ qh,
    _Float16* __restrict__ kth, _Float16* __restrict__ vth) {
  int idx = blockIdx.x * blockDim.x + threadIdx.x;
  int kk = idx & 31;
  int h  = (idx >> 5) & 15;
  int n  = (idx >> 9) & 2047;
  int b  = idx >> 20;

  size_t base_in = ((size_t)(b * N_SEQ + n)) * DM + h * DH;
  float q_re = (float)q[base_in + 2 * kk], q_im = (float)q[base_in + 2 * kk + 1];
  float k_re = (float)k[base_in + 2 * kk], k_im = (float)k[base_in + 2 * kk + 1];

  float cp = cosT[n * 32 + kk], sp = sinT[n * 32 + kk];

  float qt_re = cp * q_re + sp * q_im;
  float qt_im = cp * q_im - sp * q_re;
  float ktr   = cp * k_re + sp * k_im;
  float kti   = cp * k_im - sp * k_re;

  float wr = wre[kk], wi = wim[kk];
  float qh_re = wr * qt_re - wi * qt_im;
  float qh_im = wr * qt_im + wi * qt_re;

  float sj = 0.125f * sqrtf(1.0f + (float)n);

  size_t base_out = ((size_t)((b * H_HEADS + h) * N_SEQ + n)) * DH;
  qh[base_out + kk]      = qh_re;
  qh[base_out + 32 + kk] = qh_im;
  kth[base_out + kk]      = (_Float16)(ktr * sj);
  kth[base_out + 32 + kk] = (_Float16)(kti * sj);
  vth[base_out + 2 * kk]     = v[base_in + 2 * kk];
  vth[base_out + 2 * kk + 1] = v[base_in + 2 * kk + 1];
}

// ---------- attention: 8 Q-rows/block, fp16 K/V, fused radix pass 1 ----------
__global__ __launch_bounds__(256) void attn_kernel(const float* __restrict__ qh,
                                                   const _Float16* __restrict__ kth,
                                                   const _Float16* __restrict__ vth,
                                                   _Float16* __restrict__ oh) {
  __shared__ unsigned short sS[TQ][N_SEQ];          // 32 KB fp16 scores
  __shared__ __align__(16) unsigned char uni[KT * 72 * 2];  // 9.2 KB union
  __shared__ unsigned hist[TQ][128];                // 4 KB packed 16-bit counts
  __shared__ float rowm[TQ], rowsum[TQ];
  __shared__ unsigned cnt[TQ], thrk[TQ];
  __shared__ int sh_b[TQ], sh_k[TQ];

  _Float16 (*ktile)[72] = (_Float16(*)[72])uni;             // phase 1
  unsigned short (*lst)[CAP] = (unsigned short(*)[CAP])uni; // phase 3+

  const int tile = gridDim.x - 1 - blockIdx.x;  // heavy blocks first
  const int bh   = blockIdx.y;                  // 0..31
  const int i0   = tile * TQ;
  const int tid  = threadIdx.x;

#pragma unroll
  for (int u = 0; u < 4; ++u) ((unsigned*)hist)[u * 256 + tid] = 0;

  // ---- phase 1: scores (fp16 dot2, K pre-scaled) + fused hi-byte histogram --
  const int jl = tid & 63;
  const int rg = tid >> 6;
  const int r0 = rg * 2, r1 = r0 + 1;
  const int i_r0 = i0 + r0, i_r1 = i0 + r1;

  const float* q0 = qh + ((size_t)(bh * N_SEQ + i_r0)) * DH;
  const float* q1 = qh + ((size_t)(bh * N_SEQ + i_r1)) * DH;
  half2_t qa[32], qb[32];
#pragma unroll
  for (int d = 0; d < 16; ++d) {
    float4 t4 = ((const float4*)q0)[d];
    half2_t a0; a0[0] = (_Float16)t4.x; a0[1] = (_Float16)t4.y;
    half2_t a1; a1[0] = (_Float16)t4.z; a1[1] = (_Float16)t4.w;
    qa[2 * d] = a0; qa[2 * d + 1] = a1;
    float4 u4 = ((const float4*)q1)[d];
    half2_t b0; b0[0] = (_Float16)u4.x; b0[1] = (_Float16)u4.y;
    half2_t b1; b1[0] = (_Float16)u4.z; b1[1] = (_Float16)u4.w;
    qb[2 * d] = b0; qb[2 * d + 1] = b1;
  }
  const float rs0 = rsqrtf(1.0f + (float)i_r0);
  const float rs1 = rsqrtf(1.0f + (float)i_r1);

  const int ntile = (i0 + TQ + KT - 1) / KT;
  float mx0 = -INFINITY, mx1 = -INFINITY;
  for (int t = 0; t < ntile; ++t) {
    const int j0 = t * KT;
    __syncthreads();
    // stage 64 fp16 K rows (8 KB), coalesced 16B chunks, stride 72 halves
#pragma unroll
    for (int u = 0; u < 2; ++u) {
      int idx = u * 256 + tid;  // 512 chunks of 8 halves
      int row = idx >> 3, c8 = idx & 7;
      *(half8_t*)&ktile[row][c8 * 8] =
          *(const half8_t*)(kth + ((size_t)(bh * N_SEQ + j0 + row)) * DH + c8 * 8);
    }
    __syncthreads();
    const int j = j0 + jl;
    float dot0 = 0.f, dot1 = 0.f;
    const _Float16* krow = ktile[jl];
#pragma unroll
    for (int d8 = 0; d8 < 8; ++d8) {
      half8_t kv = *(const half8_t*)(krow + d8 * 8);
      half2_t k0; k0[0] = kv[0]; k0[1] = kv[1];
      half2_t k1; k1[0] = kv[2]; k1[1] = kv[3];
      half2_t k2; k2[0] = kv[4]; k2[1] = kv[5];
      half2_t k3; k3[0] = kv[6]; k3[1] = kv[7];
      dot0 = FDOT2(qa[4 * d8 + 0], k0, dot0);
      dot0 = FDOT2(qa[4 * d8 + 1], k1, dot0);
      dot0 = FDOT2(qa[4 * d8 + 2], k2, dot0);
      dot0 = FDOT2(qa[4 * d8 + 3], k3, dot0);
      dot1 = FDOT2(qb[4 * d8 + 0], k0, dot1);
      dot1 = FDOT2(qb[4 * d8 + 1], k1, dot1);
      dot1 = FDOT2(qb[4 * d8 + 2], k2, dot1);
      dot1 = FDOT2(qb[4 * d8 + 3], k3, dot1);
    }
    const float sc0 = dot0 * rs0;
    const float sc1 = dot1 * rs1;
    unsigned short us0 = h2us((_Float16)sc0);
    unsigned short us1 = h2us((_Float16)sc1);
    sS[r0][j] = us0;
    sS[r1][j] = us1;
    if (j <= i_r0) {
      mx0 = fmaxf(mx0, sc0);
      unsigned key = okey16(us0);
      atomicAdd(&hist[r0][(key >> 8) >> 1], 1u << (((key >> 8) & 1) * 16));
    }
    if (j <= i_r1) {
      mx1 = fmaxf(mx1, sc1);
      unsigned key = okey16(us1);
      atomicAdd(&hist[r1][(key >> 8) >> 1], 1u << (((key >> 8) & 1) * 16));
    }
  }
#pragma unroll
  for (int mgap = 32; mgap; mgap >>= 1) {
    mx0 = fmaxf(mx0, __shfl_xor(mx0, mgap));
    mx1 = fmaxf(mx1, __shfl_xor(mx1, mgap));
  }
  if (jl == 0) { rowm[r0] = mx0; rowm[r1] = mx1; }
  __syncthreads();

  // ---- select hi byte ----
  if (tid < TQ) {
    const int i_r = i0 + tid, L = i_r + 1;
    if (L > TOPK) {
      int cum = 0, b = 255;
      for (; b > 0; --b) {
        int h = (hist[tid][b >> 1] >> ((b & 1) * 16)) & 0xffff;
        if (cum + h >= TOPK) break;
        cum += h;
      }
      sh_b[tid] = b; sh_k[tid] = TOPK - cum;
    }
  }
  __syncthreads();
#pragma unroll
  for (int u = 0; u < 4; ++u) ((unsigned*)hist)[u * 256 + tid] = 0;
  __syncthreads();

  // ---- refine pass: lo byte within boundary bucket ----
  {
    const int r = tid >> 5, ts = tid & 31;
    const int i_r = i0 + r, L = i_r + 1;
    if (L > TOPK) {
      const unsigned bhi = (unsigned)sh_b[r];
      for (int j = ts; j <= i_r; j += 32) {
        unsigned key = okey16(sS[r][j]);
        if ((key >> 8) == bhi)
          atomicAdd(&hist[r][(key & 255) >> 1], 1u << ((key & 1) * 16));
      }
    }
  }
  __syncthreads();
  if (tid < TQ) {
    const int i_r = i0 + tid, L = i_r + 1;
    unsigned tk = 0;
    if (L > TOPK) {
      int krem = sh_k[tid], cum = 0, b = 255;
      for (; b > 0; --b) {
        int h = (hist[tid][b >> 1] >> ((b & 1) * 16)) & 0xffff;
        if (cum + h >= krem) break;
        cum += h;
      }
      tk = ((unsigned)sh_b[tid] << 8) | (unsigned)b;
    }
    thrk[tid] = tk;
    cnt[tid] = 0;
  }
  __syncthreads();

  // ---- masked exp + sum + survivor compaction (lst aliases ktile) ----
  {
    const int r = tid >> 5, ts = tid & 31;
    const int i_r = i0 + r;
    const unsigned tk = thrk[r];
    const float m = rowm[r];
    float lsum = 0.f;
    for (int j = ts; j <= i_r; j += 32) {
      unsigned short us = sS[r][j];
      if (okey16(us) >= tk) {
        float p = expf((float)us2h(us) - m);
        lsum += p;
        unsigned pos = atomicAdd(&cnt[r], 1u);
        if (pos < CAP) lst[r][pos] = (unsigned short)j;
      }
    }
#pragma unroll
    for (int mgap = 16; mgap; mgap >>= 1) lsum += __shfl_xor(lsum, mgap);
    if (ts == 0) rowsum[r] = lsum;
  }
  __syncthreads();

  // ---- sparse p @ V ----
  const int w = tid >> 6;
  const int lane = tid & 63;
  for (int rr = w; rr < TQ; rr += 4) {
    int n = (int)cnt[rr];
    if (n > CAP) n = CAP;
    const float m = rowm[rr];
    const float inv = 1.0f / rowsum[rr];
    float acc = 0.f;
    for (int s = 0; s < n; ++s) {
      const int jj = lst[rr][s];
      const float p = expf((float)us2h(sS[rr][jj]) - m);
      acc += p * (float)vth[((size_t)(bh * N_SEQ + jj)) * DH + lane];
    }
    const int b = bh >> 4, h = bh & 15;
    const int i = i0 + rr;
    oh[((size_t)(b * N_SEQ + i)) * DM + h * DH + lane] = (_Float16)(acc * inv);
  }
}

// ---------- launch ----------
extern "C" void kernel_launch(void* const* d_in, const int* in_sizes, int n_in,
                              void* d_out, int out_size, void* d_ws, size_t ws_size,
                              hipStream_t stream) {
  const float* x  = (const float*)d_in[0];
  const float* Wq = (const float*)d_in[1];
  const float* Wk = (const float*)d_in[2];
  const float* Wv = (const float*)d_in[3];
  const float* Wo = (const float*)d_in[4];
  float* out = (float*)d_out;
  char* ws = (char*)d_ws;

  const size_t MAT = (size_t)B_SZ * N_SEQ * DM;  // 4,194,304 elements
  const size_t WSZ = (size_t)DM * DM;            // 1,048,576

  float*    qh   = (float*)ws;                       ws += MAT * 4;   // 16 MB
  _Float16* xh   = (_Float16*)ws;                    ws += MAT * 2;   // 8 MB
  _Float16* qf   = (_Float16*)ws;                    ws += MAT * 2;
  _Float16* kf   = (_Float16*)ws;                    ws += MAT * 2;
  _Float16* vf   = (_Float16*)ws;                    ws += MAT * 2;
  _Float16* kth  = (_Float16*)ws;                    ws += MAT * 2;
  _Float16* vth  = (_Float16*)ws;                    ws += MAT * 2;
  _Float16* Wt0  = (_Float16*)ws;                    ws += WSZ * 2;
  _Float16* Wt1  = (_Float16*)ws;                    ws += WSZ * 2;
  _Float16* Wt2  = (_Float16*)ws;                    ws += WSZ * 2;
  _Float16* Wt3  = (_Float16*)ws;                    ws += WSZ * 2;
  float*    wre  = (float*)ws;                       ws += KC * 4;
  float*    wim  = (float*)ws;                       ws += KC * 4;
  float*    cosT = (float*)ws;                       ws += (size_t)N_SEQ * KC * 4;
  float*    sinT = (float*)ws;                       ws += (size_t)N_SEQ * KC * 4;
  _Float16* oh   = xh;  // xh dead after QKV GEMM; reuse for attn output

  const_kernel<<<1, 32, 0, stream>>>(wre, wim);
  rope_kernel<<<(N_SEQ * KC) / 256, 256, 0, stream>>>(cosT, sinT);
  cast_x<<<(int)(MAT / 4 / 256), 256, 0, stream>>>(x, xh);
  transpose_cast<<<dim3(16, 16, 4), 256, 0, stream>>>(Wq, Wk, Wv, Wo,
                                                      Wt0, Wt1, Wt2, Wt3);
  gemm_qkv_mfma<<<dim3(32, 8, 3), 256, 0, stream>>>(xh, Wt0, Wt1, Wt2,
                                                    qf, kf, vf);
  transform_kernel<<<(B_SZ * N_SEQ * H_HEADS * KC) / 256, 256, 0, stream>>>(
      qf, kf, vf, wre, wim, cosT, sinT, qh, kth, vth);
  attn_kernel<<<dim3(N_SEQ / TQ, B_SZ * H_HEADS), 256, 0, stream>>>(
      qh, kth, vth, oh);
  gemm_out_mfma<<<dim3(32, 8, 1), 256, 0, stream>>>(oh, Wt3, out);
}

// Round 5
// 878.731 us; speedup vs baseline: 4.0745x; 1.0462x over previous
//
#include <hip/hip_runtime.h>
#include <math.h>

#define B_SZ 2
#define N_SEQ 2048
#define DM 1024
#define H_HEADS 16
#define DH 64
#define KC 32
#define TOPK 100
#define TQ 8
#define KT 64
#define CAP 256

typedef _Float16 half2_t __attribute__((ext_vector_type(2)));
typedef _Float16 half4_t __attribute__((ext_vector_type(4)));
typedef _Float16 half8_t __attribute__((ext_vector_type(8)));
typedef float floatx4 __attribute__((ext_vector_type(4)));

// ---------- helpers ----------
__device__ __forceinline__ unsigned short h2us(_Float16 h) {
  unsigned short u; __builtin_memcpy(&u, &h, 2); return u;
}
__device__ __forceinline__ _Float16 us2h(unsigned short u) {
  _Float16 h; __builtin_memcpy(&h, &u, 2); return h;
}
__device__ __forceinline__ unsigned okey16(unsigned short us) {
  return (us & 0x8000u) ? (unsigned)(unsigned short)~us
                        : (unsigned)(us | 0x8000u);
}

// async global->LDS, 16 B per lane; lds_base must be wave-uniform
__device__ __forceinline__ void stage16(const _Float16* g, _Float16* lds_base,
                                        int lane) {
#if __has_builtin(__builtin_amdgcn_global_load_lds)
  __builtin_amdgcn_global_load_lds(
      (const __attribute__((address_space(1))) void*)g,
      (__attribute__((address_space(3))) void*)lds_base, 16, 0, 0);
#else
  *(half8_t*)(lds_base + lane * 8) = *(const half8_t*)g;
#endif
}

// ---------- constants: Riemann-zero weights ----------
__global__ void const_kernel(float* __restrict__ wre, float* __restrict__ wim) {
  __shared__ double g0s;
  const int k = threadIdx.x;  // 32 threads
  const double PI = 3.14159265358979323846;
  const double E_ = 2.71828182845904523536;
  double n = (double)(k + 1);
  double t = 10.0 + 6.0 * n;
  for (int it = 0; it < 60; ++it) {
    double f  = t / (2.0 * PI) * log(t / (2.0 * PI * E_)) - (n - 0.875);
    double fp = log(t / (2.0 * PI)) / (2.0 * PI);
    t = t - f / fp;
  }
  if (k == 0) g0s = t;
  __syncthreads();
  double g = t / g0s;
  double denom = 0.25 + g * g;
  wre[k] = (float)(0.5 / denom);
  wim[k] = (float)(-g / denom);
}

// ---------- RoPE tables ----------
__global__ __launch_bounds__(256) void rope_kernel(float* __restrict__ cosT,
                                                   float* __restrict__ sinT) {
  int idx = blockIdx.x * 256 + threadIdx.x;  // 65536 = 2048*32
  int kk = idx & 31, n = idx >> 5;
  double inv_freq = pow(10000.0, -(double)kk / 32.0);
  double ph = (double)n * inv_freq;
  cosT[idx] = (float)cos(ph);
  sinT[idx] = (float)sin(ph);
}

// ---------- cast x fp32 -> fp16 ----------
__global__ __launch_bounds__(256) void cast_x(const float* __restrict__ x,
                                              _Float16* __restrict__ xh) {
  int idx = blockIdx.x * 256 + threadIdx.x;
  float4 v = ((const float4*)x)[idx];
  half4_t h;
  h[0] = (_Float16)v.x; h[1] = (_Float16)v.y;
  h[2] = (_Float16)v.z; h[3] = (_Float16)v.w;
  ((half4_t*)xh)[idx] = h;
}

// ---------- transpose-cast W (fp32 [k][n]) -> Wt (fp16 [n][k]) ----------
__global__ __launch_bounds__(256) void transpose_cast(
    const float* __restrict__ W0, const float* __restrict__ W1,
    const float* __restrict__ W2, const float* __restrict__ W3,
    _Float16* __restrict__ T0, _Float16* __restrict__ T1,
    _Float16* __restrict__ T2, _Float16* __restrict__ T3) {
  __shared__ float t[64][65];
  const float* W; _Float16* T;
  switch (blockIdx.z) {
    case 0: W = W0; T = T0; break;
    case 1: W = W1; T = T1; break;
    case 2: W = W2; T = T2; break;
    default: W = W3; T = T3; break;
  }
  const int bx = blockIdx.x;  // k block
  const int by = blockIdx.y;  // n block
  const int tid = threadIdx.x;
  const int c = tid & 15, rr = tid >> 4;
#pragma unroll
  for (int i = 0; i < 4; ++i) {
    int k = rr + i * 16;
    float4 v = *(const float4*)(W + (size_t)(bx * 64 + k) * DM + by * 64 + c * 4);
    t[k][c * 4 + 0] = v.x; t[k][c * 4 + 1] = v.y;
    t[k][c * 4 + 2] = v.z; t[k][c * 4 + 3] = v.w;
  }
  __syncthreads();
#pragma unroll
  for (int i = 0; i < 4; ++i) {
    int n = rr + i * 16;
    half4_t h;
    h[0] = (_Float16)t[c * 4 + 0][n];
    h[1] = (_Float16)t[c * 4 + 1][n];
    h[2] = (_Float16)t[c * 4 + 2][n];
    h[3] = (_Float16)t[c * 4 + 3][n];
    *(half4_t*)(T + (size_t)(by * 64 + n) * DM + bx * 64 + c * 4) = h;
  }
}

// ---------- f16 MFMA GEMM: C[M][1024] = A[M][1024] @ Bt[1024][1024]^T ----------
template <typename OutT>
__device__ __forceinline__ void gemm_mfma_body(const _Float16* __restrict__ A,
                                               const _Float16* __restrict__ Bt,
                                               OutT* __restrict__ C) {
  __shared__ _Float16 As[128 * 32];
  __shared__ _Float16 Bs[128 * 32];
  const int tid = threadIdx.x;
  const int wave = tid >> 6, lane = tid & 63;
  const int wm = wave >> 1, wn = wave & 1;
  const int bm = blockIdx.x * 128, bn = blockIdx.y * 128;
  const int lrow = lane >> 2;       // 0..15 within a 16-row segment
  const int lkb = (lane & 3) * 8;   // k element offset of this lane's 16B
  const int l16 = lane & 15, lq = lane >> 4;
  floatx4 acc[4][4] = {};

  for (int k0 = 0; k0 < DM; k0 += 32) {
    __syncthreads();
#pragma unroll
    for (int s2 = 0; s2 < 2; ++s2) {
      const int seg = wave * 2 + s2;  // 16-row segment of the 128-row tile
      stage16(A + (size_t)(bm + seg * 16 + lrow) * DM + k0 + lkb,
              As + seg * 512, lane);
      stage16(Bt + (size_t)(bn + seg * 16 + lrow) * DM + k0 + lkb,
              Bs + seg * 512, lane);
    }
    __syncthreads();
    half8_t af[4], bf[4];
#pragma unroll
    for (int mi = 0; mi < 4; ++mi)
      af[mi] = *(const half8_t*)(As + (wm * 64 + mi * 16 + l16) * 32 + lq * 8);
#pragma unroll
    for (int ni = 0; ni < 4; ++ni)
      bf[ni] = *(const half8_t*)(Bs + (wn * 64 + ni * 16 + l16) * 32 + lq * 8);
#pragma unroll
    for (int mi = 0; mi < 4; ++mi)
#pragma unroll
      for (int ni = 0; ni < 4; ++ni)
        acc[mi][ni] = __builtin_amdgcn_mfma_f32_16x16x32_f16(
            af[mi], bf[ni], acc[mi][ni], 0, 0, 0);
  }
  // epilogue: C/D layout col=lane&15, row=(lane>>4)*4+reg  [m89-verified]
#pragma unroll
  for (int mi = 0; mi < 4; ++mi)
#pragma unroll
    for (int ni = 0; ni < 4; ++ni) {
      const int col = bn + wn * 64 + ni * 16 + l16;
#pragma unroll
      for (int r = 0; r < 4; ++r) {
        const int row = bm + wm * 64 + mi * 16 + lq * 4 + r;
        C[(size_t)row * DM + col] = (OutT)acc[mi][ni][r];
      }
    }
}

__global__ __launch_bounds__(256) void gemm_qkv_mfma(
    const _Float16* __restrict__ xh, const _Float16* __restrict__ Wt0,
    const _Float16* __restrict__ Wt1, const _Float16* __restrict__ Wt2,
    _Float16* __restrict__ q, _Float16* __restrict__ k,
    _Float16* __restrict__ v) {
  const _Float16* Bt; _Float16* C;
  if (blockIdx.z == 0)      { Bt = Wt0; C = q; }
  else if (blockIdx.z == 1) { Bt = Wt1; C = k; }
  else                      { Bt = Wt2; C = v; }
  gemm_mfma_body<_Float16>(xh, Bt, C);
}

__global__ __launch_bounds__(256) void gemm_out_mfma(
    const _Float16* __restrict__ A, const _Float16* __restrict__ Bt,
    float* __restrict__ C) {
  gemm_mfma_body<float>(A, Bt, C);
}

// ---------- RoPE + w-weighting + layout transform (fp16 in, mixed out) ------
// kth rows pre-scaled by 0.125*sqrt(1+n); vth fp16; qh fp32
__global__ __launch_bounds__(256) void transform_kernel(
    const _Float16* __restrict__ q, const _Float16* __restrict__ k,
    const _Float16* __restrict__ v, const float* __restrict__ wre,
    const float* __restrict__ wim, const float* __restrict__ cosT,
    const float* __restrict__ sinT, float* __restrict__ qh,
    _Float16* __restrict__ kth, _Float16* __restrict__ vth) {
  int idx = blockIdx.x * blockDim.x + threadIdx.x;
  int kk = idx & 31;
  int h  = (idx >> 5) & 15;
  int n  = (idx >> 9) & 2047;
  int b  = idx >> 20;

  size_t base_in = ((size_t)(b * N_SEQ + n)) * DM + h * DH;
  float q_re = (float)q[base_in + 2 * kk], q_im = (float)q[base_in + 2 * kk + 1];
  float k_re = (float)k[base_in + 2 * kk], k_im = (float)k[base_in + 2 * kk + 1];

  float cp = cosT[n * 32 + kk], sp = sinT[n * 32 + kk];

  float qt_re = cp * q_re + sp * q_im;
  float qt_im = cp * q_im - sp * q_re;
  float ktr   = cp * k_re + sp * k_im;
  float kti   = cp * k_im - sp * k_re;

  float wr = wre[kk], wi = wim[kk];
  float qh_re = wr * qt_re - wi * qt_im;
  float qh_im = wr * qt_im + wi * qt_re;

  float sj = 0.125f * sqrtf(1.0f + (float)n);

  size_t base_out = ((size_t)((b * H_HEADS + h) * N_SEQ + n)) * DH;
  qh[base_out + kk]      = qh_re;
  qh[base_out + 32 + kk] = qh_im;
  kth[base_out + kk]      = (_Float16)(ktr * sj);
  kth[base_out + 32 + kk] = (_Float16)(kti * sj);
  vth[base_out + 2 * kk]     = v[base_in + 2 * kk];
  vth[base_out + 2 * kk + 1] = v[base_in + 2 * kk + 1];
}

// ---------- attention: 8 Q-rows/block, MFMA scores, fused radix pass 1 ------
__global__ __launch_bounds__(256) void attn_kernel(const float* __restrict__ qh,
                                                   const _Float16* __restrict__ kth,
                                                   const _Float16* __restrict__ vth,
                                                   _Float16* __restrict__ oh) {
  __shared__ unsigned short sS[TQ][N_SEQ];              // 32 KB fp16 scores
  __shared__ __align__(16) _Float16 ktile[KT][76];      // 9.5 KB K tile
  __shared__ unsigned hist[TQ][128];                    // 4 KB packed counts
  __shared__ float mredw[4][TQ];
  __shared__ float rowm[TQ], rowsum[TQ];
  __shared__ unsigned cnt[TQ], thrk[TQ];
  __shared__ int sh_b[TQ], sh_k[TQ];

  unsigned short (*lst)[CAP] = (unsigned short(*)[CAP])ktile;  // phase 3+ alias

  const int tile = gridDim.x - 1 - blockIdx.x;  // heavy blocks first
  const int bh   = blockIdx.y;                  // 0..31
  const int i0   = tile * TQ;
  const int tid  = threadIdx.x;

  // zero the pass-1 histogram (visible after first barrier in score loop)
#pragma unroll
  for (int u = 0; u < 4; ++u) ((unsigned*)hist)[u * 256 + tid] = 0;

  // ---- phase 1: MFMA scores (Q pre-scaled by rsqrt(1+i); K carries
  //      0.125*sqrt(1+j)) + fused hi-byte histogram ----
  const int wv = tid >> 6, lane = tid & 63;
  const int l16 = lane & 15, lq = lane >> 4;

  // A-fragment: A[m=l16][k=lq*8+j]; rows >= TQ are zero
  half8_t af0 = {}, af1 = {};
  if (l16 < TQ) {
    const float* qrow = qh + ((size_t)(bh * N_SEQ + i0 + l16)) * DH;
    const float rs = rsqrtf(1.0f + (float)(i0 + l16));
    float4 a0 = *(const float4*)(qrow + lq * 8);
    float4 a1 = *(const float4*)(qrow + lq * 8 + 4);
    float4 b0 = *(const float4*)(qrow + 32 + lq * 8);
    float4 b1 = *(const float4*)(qrow + 32 + lq * 8 + 4);
    af0[0] = (_Float16)(a0.x * rs); af0[1] = (_Float16)(a0.y * rs);
    af0[2] = (_Float16)(a0.z * rs); af0[3] = (_Float16)(a0.w * rs);
    af0[4] = (_Float16)(a1.x * rs); af0[5] = (_Float16)(a1.y * rs);
    af0[6] = (_Float16)(a1.z * rs); af0[7] = (_Float16)(a1.w * rs);
    af1[0] = (_Float16)(b0.x * rs); af1[1] = (_Float16)(b0.y * rs);
    af1[2] = (_Float16)(b0.z * rs); af1[3] = (_Float16)(b0.w * rs);
    af1[4] = (_Float16)(b1.x * rs); af1[5] = (_Float16)(b1.y * rs);
    af1[6] = (_Float16)(b1.z * rs); af1[7] = (_Float16)(b1.w * rs);
  }

  float mx[4] = {-INFINITY, -INFINITY, -INFINITY, -INFINITY};
  const int ntile = (i0 + TQ + KT - 1) / KT;
  for (int t = 0; t < ntile; ++t) {
    const int j0 = t * KT;
    __syncthreads();  // prev consumers done (covers hist zero on t==0)
    // stage 64 fp16 K rows (8 KB), coalesced 16B chunks, stride 76 halves
#pragma unroll
    for (int u = 0; u < 2; ++u) {
      int idx = u * 256 + tid;  // 512 chunks of 8 halves
      int row = idx >> 3, c8 = idx & 7;
      *(half8_t*)&ktile[row][c8 * 8] =
          *(const half8_t*)(kth + ((size_t)(bh * N_SEQ + j0 + row)) * DH + c8 * 8);
    }
    __syncthreads();
    // B-fragment: B[n=l16 within wave's 16-col group][k=lq*8+j]
    half8_t bf0 = *(const half8_t*)&ktile[wv * 16 + l16][lq * 8];
    half8_t bf1 = *(const half8_t*)&ktile[wv * 16 + l16][32 + lq * 8];
    floatx4 acc = {};
    acc = __builtin_amdgcn_mfma_f32_16x16x32_f16(af0, bf0, acc, 0, 0, 0);
    acc = __builtin_amdgcn_mfma_f32_16x16x32_f16(af1, bf1, acc, 0, 0, 0);
    // C/D: col=l16, row=lq*4+r; valid rows 0..7 <=> lq<2
    const int jc = j0 + wv * 16 + l16;
    if (lq < 2) {
#pragma unroll
      for (int r = 0; r < 4; ++r) {
        const int row = lq * 4 + r;
        const float sc = acc[r];
        const unsigned short us = h2us((_Float16)sc);
        sS[row][jc] = us;
        if (jc <= i0 + row) {
          mx[r] = fmaxf(mx[r], sc);
          const unsigned key = okey16(us);
          atomicAdd(&hist[row][(key >> 8) >> 1], 1u << (((key >> 8) & 1) * 16));
        }
      }
    }
  }
  // max reduce across the 16 lanes (l16) sharing each row
#pragma unroll
  for (int g = 1; g <= 8; g <<= 1)
#pragma unroll
    for (int r = 0; r < 4; ++r) mx[r] = fmaxf(mx[r], __shfl_xor(mx[r], g));
  if (lq < 2 && l16 == 0)
#pragma unroll
    for (int r = 0; r < 4; ++r) mredw[wv][lq * 4 + r] = mx[r];
  __syncthreads();
  if (tid < TQ)
    rowm[tid] = fmaxf(fmaxf(mredw[0][tid], mredw[1][tid]),
                      fmaxf(mredw[2][tid], mredw[3][tid]));
  __syncthreads();

  // ---- select hi byte ----
  if (tid < TQ) {
    const int i_r = i0 + tid, L = i_r + 1;
    if (L > TOPK) {
      int cum = 0, b = 255;
      for (; b > 0; --b) {
        int h = (hist[tid][b >> 1] >> ((b & 1) * 16)) & 0xffff;
        if (cum + h >= TOPK) break;
        cum += h;
      }
      sh_b[tid] = b; sh_k[tid] = TOPK - cum;
    }
  }
  __syncthreads();
#pragma unroll
  for (int u = 0; u < 4; ++u) ((unsigned*)hist)[u * 256 + tid] = 0;
  __syncthreads();

  // ---- refine pass: lo byte within boundary bucket ----
  {
    const int r = tid >> 5, ts = tid & 31;
    const int i_r = i0 + r, L = i_r + 1;
    if (L > TOPK) {
      const unsigned bhi = (unsigned)sh_b[r];
      for (int j = ts; j <= i_r; j += 32) {
        unsigned key = okey16(sS[r][j]);
        if ((key >> 8) == bhi)
          atomicAdd(&hist[r][(key & 255) >> 1], 1u << ((key & 1) * 16));
      }
    }
  }
  __syncthreads();
  if (tid < TQ) {
    const int i_r = i0 + tid, L = i_r + 1;
    unsigned tk = 0;
    if (L > TOPK) {
      int krem = sh_k[tid], cum = 0, b = 255;
      for (; b > 0; --b) {
        int h = (hist[tid][b >> 1] >> ((b & 1) * 16)) & 0xffff;
        if (cum + h >= krem) break;
        cum += h;
      }
      tk = ((unsigned)sh_b[tid] << 8) | (unsigned)b;
    }
    thrk[tid] = tk;
    cnt[tid] = 0;
  }
  __syncthreads();

  // ---- masked exp + sum + survivor compaction (lst aliases ktile) ----
  {
    const int r = tid >> 5, ts = tid & 31;
    const int i_r = i0 + r;
    const unsigned tk = thrk[r];
    const float m = rowm[r];
    float lsum = 0.f;
    for (int j = ts; j <= i_r; j += 32) {
      unsigned short us = sS[r][j];
      if (okey16(us) >= tk) {
        float p = expf((float)us2h(us) - m);
        lsum += p;
        unsigned pos = atomicAdd(&cnt[r], 1u);
        if (pos < CAP) lst[r][pos] = (unsigned short)j;
      }
    }
#pragma unroll
    for (int mgap = 16; mgap; mgap >>= 1) lsum += __shfl_xor(lsum, mgap);
    if (ts == 0) rowsum[r] = lsum;
  }
  __syncthreads();

  // ---- sparse p @ V ----
  const int w = tid >> 6;
  const int lane_d = tid & 63;
  for (int rr = w; rr < TQ; rr += 4) {
    int n = (int)cnt[rr];
    if (n > CAP) n = CAP;
    const float m = rowm[rr];
    const float inv = 1.0f / rowsum[rr];
    float acc = 0.f;
    for (int s = 0; s < n; ++s) {
      const int jj = lst[rr][s];
      const float p = expf((float)us2h(sS[rr][jj]) - m);
      acc += p * (float)vth[((size_t)(bh * N_SEQ + jj)) * DH + lane_d];
    }
    const int b = bh >> 4, h = bh & 15;
    const int i = i0 + rr;
    oh[((size_t)(b * N_SEQ + i)) * DM + h * DH + lane_d] = (_Float16)(acc * inv);
  }
}

// ---------- launch ----------
extern "C" void kernel_launch(void* const* d_in, const int* in_sizes, int n_in,
                              void* d_out, int out_size, void* d_ws, size_t ws_size,
                              hipStream_t stream) {
  const float* x  = (const float*)d_in[0];
  const float* Wq = (const float*)d_in[1];
  const float* Wk = (const float*)d_in[2];
  const float* Wv = (const float*)d_in[3];
  const float* Wo = (const float*)d_in[4];
  float* out = (float*)d_out;
  char* ws = (char*)d_ws;

  const size_t MAT = (size_t)B_SZ * N_SEQ * DM;  // 4,194,304 elements
  const size_t WSZ = (size_t)DM * DM;            // 1,048,576

  float*    qh   = (float*)ws;                       ws += MAT * 4;   // 16 MB
  _Float16* xh   = (_Float16*)ws;                    ws += MAT * 2;   // 8 MB
  _Float16* qf   = (_Float16*)ws;                    ws += MAT * 2;
  _Float16* kf   = (_Float16*)ws;                    ws += MAT * 2;
  _Float16* vf   = (_Float16*)ws;                    ws += MAT * 2;
  _Float16* kth  = (_Float16*)ws;                    ws += MAT * 2;
  _Float16* vth  = (_Float16*)ws;                    ws += MAT * 2;
  _Float16* Wt0  = (_Float16*)ws;                    ws += WSZ * 2;
  _Float16* Wt1  = (_Float16*)ws;                    ws += WSZ * 2;
  _Float16* Wt2  = (_Float16*)ws;                    ws += WSZ * 2;
  _Float16* Wt3  = (_Float16*)ws;                    ws += WSZ * 2;
  float*    wre  = (float*)ws;                       ws += KC * 4;
  float*    wim  = (float*)ws;                       ws += KC * 4;
  float*    cosT = (float*)ws;                       ws += (size_t)N_SEQ * KC * 4;
  float*    sinT = (float*)ws;                       ws += (size_t)N_SEQ * KC * 4;
  _Float16* oh   = xh;  // xh dead after QKV GEMM; reuse for attn output

  const_kernel<<<1, 32, 0, stream>>>(wre, wim);
  rope_kernel<<<(N_SEQ * KC) / 256, 256, 0, stream>>>(cosT, sinT);
  cast_x<<<(int)(MAT / 4 / 256), 256, 0, stream>>>(x, xh);
  transpose_cast<<<dim3(16, 16, 4), 256, 0, stream>>>(Wq, Wk, Wv, Wo,
                                                      Wt0, Wt1, Wt2, Wt3);
  gemm_qkv_mfma<<<dim3(32, 8, 3), 256, 0, stream>>>(xh, Wt0, Wt1, Wt2,
                                                    qf, kf, vf);
  transform_kernel<<<(B_SZ * N_SEQ * H_HEADS * KC) / 256, 256, 0, stream>>>(
      qf, kf, vf, wre, wim, cosT, sinT, qh, kth, vth);
  attn_kernel<<<dim3(N_SEQ / TQ, B_SZ * H_HEADS), 256, 0, stream>>>(
      qh, kth, vth, oh);
  gemm_out_mfma<<<dim3(32, 8, 1), 256, 0, stream>>>(oh, Wt3, out);
}

// Round 6
// 707.506 us; speedup vs baseline: 5.0606x; 1.2420x over previous
//
#include <hip/hip_runtime.h>
#include <math.h>

#define B_SZ 2
#define N_SEQ 2048
#define DM 1024
#define H_HEADS 16
#define DH 64
#define KC 32
#define TOPK 100
#define TQ 16
#define KT 64
#define LCAP 320
#define FCAP 192

typedef _Float16 half2_t __attribute__((ext_vector_type(2)));
typedef _Float16 half4_t __attribute__((ext_vector_type(4)));
typedef _Float16 half8_t __attribute__((ext_vector_type(8)));
typedef float floatx4 __attribute__((ext_vector_type(4)));

// ---------- helpers ----------
__device__ __forceinline__ unsigned short h2us(_Float16 h) {
  unsigned short u; __builtin_memcpy(&u, &h, 2); return u;
}
__device__ __forceinline__ _Float16 us2h(unsigned short u) {
  _Float16 h; __builtin_memcpy(&h, &u, 2); return h;
}
__device__ __forceinline__ unsigned okey16(unsigned short us) {
  return (us & 0x8000u) ? (unsigned)(unsigned short)~us
                        : (unsigned)(us | 0x8000u);
}

// async global->LDS, 16 B per lane; lds_base must be wave-uniform
__device__ __forceinline__ void stage16(const _Float16* g, _Float16* lds_base,
                                        int lane) {
#if __has_builtin(__builtin_amdgcn_global_load_lds)
  __builtin_amdgcn_global_load_lds(
      (const __attribute__((address_space(1))) void*)g,
      (__attribute__((address_space(3))) void*)lds_base, 16, 0, 0);
#else
  *(half8_t*)(lds_base + lane * 8) = *(const half8_t*)g;
#endif
}

// ---------- constants: Riemann-zero weights ----------
__global__ void const_kernel(float* __restrict__ wre, float* __restrict__ wim) {
  __shared__ double g0s;
  const int k = threadIdx.x;  // 32 threads
  const double PI = 3.14159265358979323846;
  const double E_ = 2.71828182845904523536;
  double n = (double)(k + 1);
  double t = 10.0 + 6.0 * n;
  for (int it = 0; it < 60; ++it) {
    double f  = t / (2.0 * PI) * log(t / (2.0 * PI * E_)) - (n - 0.875);
    double fp = log(t / (2.0 * PI)) / (2.0 * PI);
    t = t - f / fp;
  }
  if (k == 0) g0s = t;
  __syncthreads();
  double g = t / g0s;
  double denom = 0.25 + g * g;
  wre[k] = (float)(0.5 / denom);
  wim[k] = (float)(-g / denom);
}

// ---------- RoPE tables ----------
__global__ __launch_bounds__(256) void rope_kernel(float* __restrict__ cosT,
                                                   float* __restrict__ sinT) {
  int idx = blockIdx.x * 256 + threadIdx.x;  // 65536 = 2048*32
  int kk = idx & 31, n = idx >> 5;
  double inv_freq = pow(10000.0, -(double)kk / 32.0);
  double ph = (double)n * inv_freq;
  cosT[idx] = (float)cos(ph);
  sinT[idx] = (float)sin(ph);
}

// ---------- cast x fp32 -> fp16 ----------
__global__ __launch_bounds__(256) void cast_x(const float* __restrict__ x,
                                              _Float16* __restrict__ xh) {
  int idx = blockIdx.x * 256 + threadIdx.x;
  float4 v = ((const float4*)x)[idx];
  half4_t h;
  h[0] = (_Float16)v.x; h[1] = (_Float16)v.y;
  h[2] = (_Float16)v.z; h[3] = (_Float16)v.w;
  ((half4_t*)xh)[idx] = h;
}

// ---------- transpose-cast W (fp32 [k][n]) -> Wt (fp16 [n][k]) ----------
__global__ __launch_bounds__(256) void transpose_cast(
    const float* __restrict__ W0, const float* __restrict__ W1,
    const float* __restrict__ W2, const float* __restrict__ W3,
    _Float16* __restrict__ T0, _Float16* __restrict__ T1,
    _Float16* __restrict__ T2, _Float16* __restrict__ T3) {
  __shared__ float t[64][65];
  const float* W; _Float16* T;
  switch (blockIdx.z) {
    case 0: W = W0; T = T0; break;
    case 1: W = W1; T = T1; break;
    case 2: W = W2; T = T2; break;
    default: W = W3; T = T3; break;
  }
  const int bx = blockIdx.x;  // k block
  const int by = blockIdx.y;  // n block
  const int tid = threadIdx.x;
  const int c = tid & 15, rr = tid >> 4;
#pragma unroll
  for (int i = 0; i < 4; ++i) {
    int k = rr + i * 16;
    float4 v = *(const float4*)(W + (size_t)(bx * 64 + k) * DM + by * 64 + c * 4);
    t[k][c * 4 + 0] = v.x; t[k][c * 4 + 1] = v.y;
    t[k][c * 4 + 2] = v.z; t[k][c * 4 + 3] = v.w;
  }
  __syncthreads();
#pragma unroll
  for (int i = 0; i < 4; ++i) {
    int n = rr + i * 16;
    half4_t h;
    h[0] = (_Float16)t[c * 4 + 0][n];
    h[1] = (_Float16)t[c * 4 + 1][n];
    h[2] = (_Float16)t[c * 4 + 2][n];
    h[3] = (_Float16)t[c * 4 + 3][n];
    *(half4_t*)(T + (size_t)(by * 64 + n) * DM + bx * 64 + c * 4) = h;
  }
}

// ---------- f16 MFMA GEMM: C[M][1024] = A[M][1024] @ Bt[1024][1024]^T ----------
template <typename OutT>
__device__ __forceinline__ void gemm_mfma_body(const _Float16* __restrict__ A,
                                               const _Float16* __restrict__ Bt,
                                               OutT* __restrict__ C) {
  __shared__ _Float16 As[128 * 32];
  __shared__ _Float16 Bs[128 * 32];
  const int tid = threadIdx.x;
  const int wave = tid >> 6, lane = tid & 63;
  const int wm = wave >> 1, wn = wave & 1;
  const int bm = blockIdx.x * 128, bn = blockIdx.y * 128;
  const int lrow = lane >> 2;       // 0..15 within a 16-row segment
  const int lkb = (lane & 3) * 8;   // k element offset of this lane's 16B
  const int l16 = lane & 15, lq = lane >> 4;
  floatx4 acc[4][4] = {};

  for (int k0 = 0; k0 < DM; k0 += 32) {
    __syncthreads();
#pragma unroll
    for (int s2 = 0; s2 < 2; ++s2) {
      const int seg = wave * 2 + s2;  // 16-row segment of the 128-row tile
      stage16(A + (size_t)(bm + seg * 16 + lrow) * DM + k0 + lkb,
              As + seg * 512, lane);
      stage16(Bt + (size_t)(bn + seg * 16 + lrow) * DM + k0 + lkb,
              Bs + seg * 512, lane);
    }
    __syncthreads();
    half8_t af[4], bf[4];
#pragma unroll
    for (int mi = 0; mi < 4; ++mi)
      af[mi] = *(const half8_t*)(As + (wm * 64 + mi * 16 + l16) * 32 + lq * 8);
#pragma unroll
    for (int ni = 0; ni < 4; ++ni)
      bf[ni] = *(const half8_t*)(Bs + (wn * 64 + ni * 16 + l16) * 32 + lq * 8);
#pragma unroll
    for (int mi = 0; mi < 4; ++mi)
#pragma unroll
      for (int ni = 0; ni < 4; ++ni)
        acc[mi][ni] = __builtin_amdgcn_mfma_f32_16x16x32_f16(
            af[mi], bf[ni], acc[mi][ni], 0, 0, 0);
  }
  // epilogue: C/D layout col=lane&15, row=(lane>>4)*4+reg  [m89-verified]
#pragma unroll
  for (int mi = 0; mi < 4; ++mi)
#pragma unroll
    for (int ni = 0; ni < 4; ++ni) {
      const int col = bn + wn * 64 + ni * 16 + l16;
#pragma unroll
      for (int r = 0; r < 4; ++r) {
        const int row = bm + wm * 64 + mi * 16 + lq * 4 + r;
        C[(size_t)row * DM + col] = (OutT)acc[mi][ni][r];
      }
    }
}

__global__ __launch_bounds__(256) void gemm_qkv_mfma(
    const _Float16* __restrict__ xh, const _Float16* __restrict__ Wt0,
    const _Float16* __restrict__ Wt1, const _Float16* __restrict__ Wt2,
    _Float16* __restrict__ q, _Float16* __restrict__ k,
    _Float16* __restrict__ v) {
  const _Float16* Bt; _Float16* C;
  if (blockIdx.z == 0)      { Bt = Wt0; C = q; }
  else if (blockIdx.z == 1) { Bt = Wt1; C = k; }
  else                      { Bt = Wt2; C = v; }
  gemm_mfma_body<_Float16>(xh, Bt, C);
}

__global__ __launch_bounds__(256) void gemm_out_mfma(
    const _Float16* __restrict__ A, const _Float16* __restrict__ Bt,
    float* __restrict__ C) {
  gemm_mfma_body<float>(A, Bt, C);
}

// ---------- RoPE + w-weighting + layout transform (fp16 in, mixed out) ------
__global__ __launch_bounds__(256) void transform_kernel(
    const _Float16* __restrict__ q, const _Float16* __restrict__ k,
    const _Float16* __restrict__ v, const float* __restrict__ wre,
    const float* __restrict__ wim, const float* __restrict__ cosT,
    const float* __restrict__ sinT, float* __restrict__ qh,
    _Float16* __restrict__ kth, _Float16* __restrict__ vth) {
  int idx = blockIdx.x * blockDim.x + threadIdx.x;
  int kk = idx & 31;
  int h  = (idx >> 5) & 15;
  int n  = (idx >> 9) & 2047;
  int b  = idx >> 20;

  size_t base_in = ((size_t)(b * N_SEQ + n)) * DM + h * DH;
  float q_re = (float)q[base_in + 2 * kk], q_im = (float)q[base_in + 2 * kk + 1];
  float k_re = (float)k[base_in + 2 * kk], k_im = (float)k[base_in + 2 * kk + 1];

  float cp = cosT[n * 32 + kk], sp = sinT[n * 32 + kk];

  float qt_re = cp * q_re + sp * q_im;
  float qt_im = cp * q_im - sp * q_re;
  float ktr   = cp * k_re + sp * k_im;
  float kti   = cp * k_im - sp * k_re;

  float wr = wre[kk], wi = wim[kk];
  float qh_re = wr * qt_re - wi * qt_im;
  float qh_im = wr * qt_im + wi * qt_re;

  float sj = 0.125f * sqrtf(1.0f + (float)n);

  size_t base_out = ((size_t)((b * H_HEADS + h) * N_SEQ + n)) * DH;
  qh[base_out + kk]      = qh_re;
  qh[base_out + 32 + kk] = qh_im;
  kth[base_out + kk]      = (_Float16)(ktr * sj);
  kth[base_out + 32 + kk] = (_Float16)(kti * sj);
  vth[base_out + 2 * kk]     = v[base_in + 2 * kk];
  vth[base_out + 2 * kk + 1] = v[base_in + 2 * kk + 1];
}

// ---------- attention: 16 Q-rows/block, 3-sweep MFMA, no score buffer ------
__global__ __launch_bounds__(256) void attn_kernel(const float* __restrict__ qh,
                                                   const _Float16* __restrict__ kth,
                                                   const _Float16* __restrict__ vth,
                                                   _Float16* __restrict__ oh) {
  __shared__ __align__(16) _Float16 ktile[KT][76];   // 9.5 KB K tile
  __shared__ unsigned hist[TQ][128];                 // 8 KB packed 16-bit counts
  __shared__ unsigned list[TQ][LCAP];                // 20 KB candidate (us<<16|j)
  __shared__ unsigned final_[TQ][FCAP];              // 12 KB survivors
  __shared__ float mredw[4][TQ];
  __shared__ float rowm[TQ], rowsum[TQ];
  __shared__ unsigned cnt[TQ], cnt2[TQ], tkA[TQ];
  __shared__ int sh_b[TQ], sh_k[TQ];
  __shared__ unsigned ovf;

  const int tile = gridDim.x - 1 - blockIdx.x;  // heavy blocks first
  const int bh   = blockIdx.y;                  // 0..31
  const int i0   = tile * TQ;
  const int tid  = threadIdx.x;
  const int wv = tid >> 6, lane = tid & 63;
  const int l16 = lane & 15, lq = lane >> 4;

  const _Float16* kbase = kth + (size_t)bh * N_SEQ * DH;
  const _Float16* vbase = vth + (size_t)bh * N_SEQ * DH;

  // ---- init ----
#pragma unroll
  for (int u = 0; u < 8; ++u) ((unsigned*)hist)[u * 256 + tid] = 0;
  if (tid < TQ) cnt[tid] = 0;
  if (tid == 0) ovf = 0;

  // ---- A-fragment: row m=l16 -> q row i0+l16, k=lq*8+j (K=64 via 2 mfma) ----
  half8_t af0, af1;
  {
    const float* qrow = qh + ((size_t)(bh * N_SEQ + i0 + l16)) * DH;
    const float rs = rsqrtf(1.0f + (float)(i0 + l16));
    float4 a0 = *(const float4*)(qrow + lq * 8);
    float4 a1 = *(const float4*)(qrow + lq * 8 + 4);
    float4 b0 = *(const float4*)(qrow + 32 + lq * 8);
    float4 b1 = *(const float4*)(qrow + 32 + lq * 8 + 4);
    af0[0] = (_Float16)(a0.x * rs); af0[1] = (_Float16)(a0.y * rs);
    af0[2] = (_Float16)(a0.z * rs); af0[3] = (_Float16)(a0.w * rs);
    af0[4] = (_Float16)(a1.x * rs); af0[5] = (_Float16)(a1.y * rs);
    af0[6] = (_Float16)(a1.z * rs); af0[7] = (_Float16)(a1.w * rs);
    af1[0] = (_Float16)(b0.x * rs); af1[1] = (_Float16)(b0.y * rs);
    af1[2] = (_Float16)(b0.z * rs); af1[3] = (_Float16)(b0.w * rs);
    af1[4] = (_Float16)(b1.x * rs); af1[5] = (_Float16)(b1.y * rs);
    af1[6] = (_Float16)(b1.z * rs); af1[7] = (_Float16)(b1.w * rs);
  }

  const int ntile = (i0 + TQ + KT - 1) / KT;
  // sweep: stage K tiles, MFMA, run epilogue(r, row, jc, score)
  auto sweep = [&](auto epi) {
    for (int t = 0; t < ntile; ++t) {
      const int j0 = t * KT;
      __syncthreads();
#pragma unroll
      for (int u = 0; u < 2; ++u) {
        int idx = u * 256 + tid;  // 512 chunks of 8 halves
        int row = idx >> 3, c8 = idx & 7;
        *(half8_t*)&ktile[row][c8 * 8] =
            *(const half8_t*)(kbase + (size_t)(j0 + row) * DH + c8 * 8);
      }
      __syncthreads();
      half8_t bf0 = *(const half8_t*)&ktile[wv * 16 + l16][lq * 8];
      half8_t bf1 = *(const half8_t*)&ktile[wv * 16 + l16][32 + lq * 8];
      floatx4 acc = {};
      acc = __builtin_amdgcn_mfma_f32_16x16x32_f16(af0, bf0, acc, 0, 0, 0);
      acc = __builtin_amdgcn_mfma_f32_16x16x32_f16(af1, bf1, acc, 0, 0, 0);
      const int jc = j0 + wv * 16 + l16;
#pragma unroll
      for (int r = 0; r < 4; ++r) epi(r, lq * 4 + r, jc, acc[r]);
    }
  };

  // ---- pass A: hi-byte histogram + row max ----
  float mx[4] = {-INFINITY, -INFINITY, -INFINITY, -INFINITY};
  sweep([&](int r, int row, int jc, float sc) {
    if (jc <= i0 + row) {
      unsigned short us = h2us((_Float16)sc);
      mx[r] = fmaxf(mx[r], sc);
      unsigned hb = okey16(us) >> 8;
      atomicAdd(&hist[row][hb >> 1], 1u << ((hb & 1) * 16));
    }
  });
#pragma unroll
  for (int g = 1; g <= 8; g <<= 1)
#pragma unroll
    for (int r = 0; r < 4; ++r) mx[r] = fmaxf(mx[r], __shfl_xor(mx[r], g));
  if (l16 == 0)
#pragma unroll
    for (int r = 0; r < 4; ++r) mredw[wv][lq * 4 + r] = mx[r];
  __syncthreads();

  // ---- select hi byte (16 threads) ----
  if (tid < TQ) {
    rowm[tid] = fmaxf(fmaxf(mredw[0][tid], mredw[1][tid]),
                      fmaxf(mredw[2][tid], mredw[3][tid]));
    const int L = i0 + tid + 1;
    if (L > TOPK) {
      int cum = 0, b = 255;
      for (; b >= 0; --b) {
        int h = (hist[tid][b >> 1] >> ((b & 1) * 16)) & 0xffff;
        if (cum + h >= TOPK) break;
        cum += h;
      }
      sh_b[tid] = b; sh_k[tid] = TOPK - cum;
    } else {
      sh_b[tid] = 0; sh_k[tid] = 0;
    }
  }
  __syncthreads();
#pragma unroll
  for (int u = 0; u < 8; ++u) ((unsigned*)hist)[u * 256 + tid] = 0;
  int bh4[4];
#pragma unroll
  for (int r = 0; r < 4; ++r) bh4[r] = sh_b[lq * 4 + r];

  // ---- pass B: collect candidates (hi >= bhi) + lo-byte hist (hi == bhi) ----
  sweep([&](int r, int row, int jc, float sc) {
    if (jc <= i0 + row) {
      unsigned short us = h2us((_Float16)sc);
      unsigned key = okey16(us);
      int hb = (int)(key >> 8);
      if (hb >= bh4[r]) {
        unsigned pos = atomicAdd(&cnt[row], 1u);
        if (pos < LCAP) list[row][pos] = ((unsigned)us << 16) | (unsigned)jc;
        if (hb == bh4[r]) {
          unsigned lb = key & 255u;
          atomicAdd(&hist[row][lb >> 1], 1u << ((lb & 1) * 16));
        }
      }
    }
  });
  __syncthreads();

  // ---- select lo byte -> exact threshold key ----
  if (tid < TQ) {
    const int L = i0 + tid + 1;
    unsigned tk = 0;
    if (L > TOPK) {
      int krem = sh_k[tid], cum = 0, b = 255;
      for (; b >= 0; --b) {
        int h = (hist[tid][b >> 1] >> ((b & 1) * 16)) & 0xffff;
        if (cum + h >= krem) break;
        cum += h;
      }
      tk = ((unsigned)sh_b[tid] << 8) | (unsigned)b;
    }
    tkA[tid] = tk;
    cnt2[tid] = 0;
    if (cnt[tid] > LCAP) atomicOr(&ovf, 1u);
  }
  __syncthreads();

  if (ovf == 0) {
    // ---- filter candidate list -> survivors + exp-sum ----
    const int r = tid >> 4, ts = tid & 15;
    const unsigned tk = tkA[r];
    const float m = rowm[r];
    const int n = (int)min(cnt[r], (unsigned)LCAP);
    float lsum = 0.f;
    for (int s = ts; s < n; s += 16) {
      unsigned e = list[r][s];
      unsigned short us = (unsigned short)(e >> 16);
      if (okey16(us) >= tk) {
        float p = expf((float)us2h(us) - m);
        lsum += p;
        unsigned pos = atomicAdd(&cnt2[r], 1u);
        if (pos < FCAP) final_[r][pos] = e;
      }
    }
#pragma unroll
    for (int g = 1; g <= 8; g <<= 1) lsum += __shfl_xor(lsum, g);
    if (ts == 0) rowsum[r] = lsum;
  } else {
    // ---- rare fallback: full rescan with exact threshold ----
    if (tid < TQ) { rowsum[tid] = 0.f; cnt2[tid] = 0; }
    __syncthreads();
    unsigned tk4[4]; float m4[4];
#pragma unroll
    for (int r = 0; r < 4; ++r) { tk4[r] = tkA[lq * 4 + r]; m4[r] = rowm[lq * 4 + r]; }
    sweep([&](int r, int row, int jc, float sc) {
      if (jc <= i0 + row) {
        unsigned short us = h2us((_Float16)sc);
        if (okey16(us) >= tk4[r]) {
          float p = expf((float)us2h(us) - m4[r]);
          atomicAdd(&rowsum[row], p);
          unsigned pos = atomicAdd(&cnt2[row], 1u);
          if (pos < FCAP) final_[row][pos] = ((unsigned)us << 16) | (unsigned)jc;
        }
      }
    });
  }
  __syncthreads();

  // ---- sparse p @ V, one wave per row ----
  for (int rr = wv; rr < TQ; rr += 4) {
    const int n = (int)min(cnt2[rr], (unsigned)FCAP);
    const float m = rowm[rr];
    const float inv = 1.0f / rowsum[rr];
    float acc = 0.f;
    for (int s = 0; s < n; ++s) {
      unsigned e = final_[rr][s];
      const int jj = (int)(e & 0xffffu);
      const float p = expf((float)us2h((unsigned short)(e >> 16)) - m);
      acc += p * (float)vbase[(size_t)jj * DH + lane];
    }
    const int b = bh >> 4, h = bh & 15;
    const int i = i0 + rr;
    oh[((size_t)(b * N_SEQ + i)) * DM + h * DH + lane] = (_Float16)(acc * inv);
  }
}

// ---------- launch ----------
extern "C" void kernel_launch(void* const* d_in, const int* in_sizes, int n_in,
                              void* d_out, int out_size, void* d_ws, size_t ws_size,
                              hipStream_t stream) {
  const float* x  = (const float*)d_in[0];
  const float* Wq = (const float*)d_in[1];
  const float* Wk = (const float*)d_in[2];
  const float* Wv = (const float*)d_in[3];
  const float* Wo = (const float*)d_in[4];
  float* out = (float*)d_out;
  char* ws = (char*)d_ws;

  const size_t MAT = (size_t)B_SZ * N_SEQ * DM;  // 4,194,304 elements
  const size_t WSZ = (size_t)DM * DM;            // 1,048,576

  float*    qh   = (float*)ws;                       ws += MAT * 4;   // 16 MB
  _Float16* xh   = (_Float16*)ws;                    ws += MAT * 2;   // 8 MB
  _Float16* qf   = (_Float16*)ws;                    ws += MAT * 2;
  _Float16* kf   = (_Float16*)ws;                    ws += MAT * 2;
  _Float16* vf   = (_Float16*)ws;                    ws += MAT * 2;
  _Float16* kth  = (_Float16*)ws;                    ws += MAT * 2;
  _Float16* vth  = (_Float16*)ws;                    ws += MAT * 2;
  _Float16* Wt0  = (_Float16*)ws;                    ws += WSZ * 2;
  _Float16* Wt1  = (_Float16*)ws;                    ws += WSZ * 2;
  _Float16* Wt2  = (_Float16*)ws;                    ws += WSZ * 2;
  _Float16* Wt3  = (_Float16*)ws;                    ws += WSZ * 2;
  float*    wre  = (float*)ws;                       ws += KC * 4;
  float*    wim  = (float*)ws;                       ws += KC * 4;
  float*    cosT = (float*)ws;                       ws += (size_t)N_SEQ * KC * 4;
  float*    sinT = (float*)ws;                       ws += (size_t)N_SEQ * KC * 4;
  _Float16* oh   = xh;  // xh dead after QKV GEMM; reuse for attn output

  const_kernel<<<1, 32, 0, stream>>>(wre, wim);
  rope_kernel<<<(N_SEQ * KC) / 256, 256, 0, stream>>>(cosT, sinT);
  cast_x<<<(int)(MAT / 4 / 256), 256, 0, stream>>>(x, xh);
  transpose_cast<<<dim3(16, 16, 4), 256, 0, stream>>>(Wq, Wk, Wv, Wo,
                                                      Wt0, Wt1, Wt2, Wt3);
  gemm_qkv_mfma<<<dim3(32, 8, 3), 256, 0, stream>>>(xh, Wt0, Wt1, Wt2,
                                                    qf, kf, vf);
  transform_kernel<<<(B_SZ * N_SEQ * H_HEADS * KC) / 256, 256, 0, stream>>>(
      qf, kf, vf, wre, wim, cosT, sinT, qh, kth, vth);
  attn_kernel<<<dim3(N_SEQ / TQ, B_SZ * H_HEADS), 256, 0, stream>>>(
      qh, kth, vth, oh);
  gemm_out_mfma<<<dim3(32, 8, 1), 256, 0, stream>>>(oh, Wt3, out);
}